// Round 14
// baseline (188.676 us; speedup 1.0000x reference)
//
#include <hip/hip_runtime.h>
#include <math.h>

// Problem constants
#define BATCH 4
#define SEQ   2048
#define HDIM  128
#define NHEAD 8
#define MROWS (BATCH*SEQ)    // 8192
#define QKVN  (3*NHEAD*HDIM) // 3072
#define YN    (NHEAD*HDIM)   // 1024
#define NROWS 65536          // 32 heads * 2048 rows

#define CS 0.12751744f   // (1/sqrt(128)) * log2(e)

using bfrag = __attribute__((ext_vector_type(8))) short;  // 8 bf16 (4 VGPRs)
using f32x4 = __attribute__((ext_vector_type(4))) float;
using s16x4 = __attribute__((ext_vector_type(4))) short;

__device__ __forceinline__ f32x4 mfma16(bfrag a, bfrag b, f32x4 c) {
    return __builtin_amdgcn_mfma_f32_16x16x32_bf16(a, b, c, 0, 0, 0);
}
__device__ __forceinline__ short f2bf(float f) {
    union { float f; unsigned u; } v; v.f = f;
    unsigned r = v.u + 0x7FFFu + ((v.u >> 16) & 1u);  // RNE
    return (short)(r >> 16);
}
__device__ __forceinline__ float bf2f(short s) {
    union { unsigned u; float f; } v; v.u = ((unsigned)(unsigned short)s) << 16;
    return v.f;
}
__device__ __forceinline__ unsigned cvtpk(float lo, float hi) {
    unsigned r;
    asm("v_cvt_pk_bf16_f32 %0, %1, %2" : "=v"(r) : "v"(lo), "v"(hi));
    return r;
}
__device__ __forceinline__ void perm32swap(unsigned &x, unsigned &y) {
    asm volatile("v_permlane32_swap_b32 %0, %1" : "+v"(x), "+v"(y));
}
__device__ __forceinline__ f32x4 z4() { f32x4 z; z[0]=0.f; z[1]=0.f; z[2]=0.f; z[3]=0.f; return z; }

// In-register P redistribution (C-layout -> A-frag layout), validated attn8/10.
__device__ __forceinline__ void redist(const float p[4][4], bool hi16,
                                       bfrag &pa0o, bfrag &pa1o) {
    unsigned pk0[2], pk1[2], pk2[2], pk3[2];
    pk0[0] = cvtpk(p[0][0], p[0][1]); pk0[1] = cvtpk(p[0][2], p[0][3]);
    pk1[0] = cvtpk(p[1][0], p[1][1]); pk1[1] = cvtpk(p[1][2], p[1][3]);
    pk2[0] = cvtpk(p[2][0], p[2][1]); pk2[1] = cvtpk(p[2][2], p[2][3]);
    pk3[0] = cvtpk(p[3][0], p[3][1]); pk3[1] = cvtpk(p[3][2], p[3][3]);
    uint4 w0, w1;
    {
        unsigned A = pk0[0], C = pk1[0];
        perm32swap(A, C);
        unsigned A16 = __shfl_xor((int)A, 16), C16 = __shfl_xor((int)C, 16);
        w0.x = hi16 ? C16 : A;
        w0.z = hi16 ? C   : A16;
        unsigned B = pk0[1], D = pk1[1];
        perm32swap(B, D);
        unsigned B16 = __shfl_xor((int)B, 16), D16 = __shfl_xor((int)D, 16);
        w0.y = hi16 ? D16 : B;
        w0.w = hi16 ? D   : B16;
    }
    {
        unsigned E = pk2[0], G = pk3[0];
        perm32swap(E, G);
        unsigned E16 = __shfl_xor((int)E, 16), G16 = __shfl_xor((int)G, 16);
        w1.x = hi16 ? G16 : E;
        w1.z = hi16 ? G   : E16;
        unsigned F = pk2[1], H = pk3[1];
        perm32swap(F, H);
        unsigned F16 = __shfl_xor((int)F, 16), H16 = __shfl_xor((int)H, 16);
        w1.y = hi16 ? H16 : F;
        w1.w = hi16 ? H   : F16;
    }
    union { uint4 u; bfrag f; } cv0, cv1;
    cv0.u = w0; cv1.u = w1;
    pa0o = cv0.f; pa1o = cv1.f;
}

// ---------------------------------------------------------------------------
// Converters
// ---------------------------------------------------------------------------
__global__ __launch_bounds__(256) void conv_x(const float* __restrict__ x, short* __restrict__ XB) {
    int i = (blockIdx.x * 256 + threadIdx.x) * 4;
    float4 v = *(const float4*)(x + i);
    s16x4 o; o[0] = f2bf(v.x); o[1] = f2bf(v.y); o[2] = f2bf(v.z); o[3] = f2bf(v.w);
    *(s16x4*)(XB + i) = o;
}
__global__ __launch_bounds__(256) void conv_qkvT(const float* __restrict__ q, short* __restrict__ qT) {
    int t = blockIdx.x * 256 + threadIdx.x;         // 3072*128
    int n = t >> 7, k = t & 127;
    qT[t] = f2bf(q[(size_t)k * QKVN + n]);
}
__global__ __launch_bounds__(256) void conv_projT(const float* __restrict__ p, short* __restrict__ pT) {
    int t = blockIdx.x * 256 + threadIdx.x;         // 128*1024
    int h = t >> 10, r = t & 1023;
    pT[t] = f2bf(p[(size_t)r * HDIM + h]);
}

// ---------------------------------------------------------------------------
// GEMM1: x @ qkv scattered into per-head Qh/Kh/Vh[(b*8+n)*2048 + s2][h]
// ---------------------------------------------------------------------------
__global__ __launch_bounds__(256) void gemm_qkv(
    const short* __restrict__ XB, const short* __restrict__ qkvT,
    short* __restrict__ Qh, short* __restrict__ Kh, short* __restrict__ Vh)
{
    const int t = threadIdx.x, lane = t & 63, w = t >> 6;
    const int lr = lane & 15, lg = lane >> 4;
    const int m0 = blockIdx.x * 128 + (w >> 1) * 64;
    const int n0 = blockIdx.y * 128 + (w & 1) * 64;

    f32x4 acc[4][4];
    #pragma unroll
    for (int i = 0; i < 4; ++i)
        #pragma unroll
        for (int j = 0; j < 4; ++j) acc[i][j] = z4();

    #pragma unroll
    for (int c = 0; c < 4; ++c) {
        bfrag a[4], bb[4];
        #pragma unroll
        for (int rt = 0; rt < 4; ++rt)
            a[rt] = *(const bfrag*)(XB + (size_t)(m0 + rt * 16 + lr) * 128 + c * 32 + lg * 8);
        #pragma unroll
        for (int nt = 0; nt < 4; ++nt)
            bb[nt] = *(const bfrag*)(qkvT + (size_t)(n0 + nt * 16 + lr) * 128 + c * 32 + lg * 8);
        #pragma unroll
        for (int rt = 0; rt < 4; ++rt)
            #pragma unroll
            for (int nt = 0; nt < 4; ++nt)
                acc[rt][nt] = mfma16(a[rt], bb[nt], acc[rt][nt]);
    }

    const int part = blockIdx.y >> 3, c8 = blockIdx.y & 7;
    short* dst = (part == 0) ? Qh : ((part == 1) ? Kh : Vh);
    #pragma unroll
    for (int rt = 0; rt < 4; ++rt)
        #pragma unroll
        for (int j = 0; j < 4; ++j) {
            int r = m0 + rt * 16 + lg * 4 + j;
            int b = r >> 11, sl = r & 2047;
            int n = sl >> 8, s2 = (sl & 255) * 8 + c8;
            size_t rowbase = ((size_t)((b * 8 + n) * 2048 + s2)) * 128;
            #pragma unroll
            for (int nt = 0; nt < 4; ++nt) {
                int h = (w & 1) * 64 + nt * 16 + lr;
                dst[rowbase + h] = f2bf(acc[rt][nt][j]);
            }
        }
}

// ---------------------------------------------------------------------------
// Transpose V per head: Vh[bn][s2][d] -> Vt[bn][d][s2].
// ---------------------------------------------------------------------------
__global__ __launch_bounds__(256) void transp_v(
    const short* __restrict__ Vh, short* __restrict__ Vt)
{
    __shared__ short Ls[64][72];
    const int bn = blockIdx.z, s20 = blockIdx.x * 64, d0 = blockIdx.y * 64;
    const int t = threadIdx.x;
    const short* src = Vh + ((size_t)bn * SEQ + s20) * 128 + d0;
    {
        int r = t >> 2, ch = (t & 3) * 16;
        *(int4*)&Ls[r][ch]     = *(const int4*)(src + (size_t)r * 128 + ch);
        *(int4*)&Ls[r][ch + 8] = *(const int4*)(src + (size_t)r * 128 + ch + 8);
    }
    __syncthreads();
    {
        int dr = t >> 2, ch = (t & 3) * 16;
        short tmp[16];
        #pragma unroll
        for (int i = 0; i < 16; ++i) tmp[i] = Ls[ch + i][dr];
        short* dp = Vt + ((size_t)bn * HDIM + d0 + dr) * SEQ + s20 + ch;
        *(int4*)dp       = *(int4*)&tmp[0];
        *(int4*)(dp + 8) = *(int4*)&tmp[8];
    }
}

// ---------------------------------------------------------------------------
// attn11: 32 q-rows/wave (QBLK=128) + STEP-split kv + attn10 machinery.
// Block g = (head bn = g&31 [XCD-affine], pair pp = (g>>5)&7, split sp = g>>8).
// Phases: tile A = 15-pp, then tile B = pp. Tile t has 2(t+1) KVBLK=64 steps;
// sp=0 runs steps 0..t, sp=1 runs steps t+1..2t+1 -> EVERY step live, 17
// uniform steps/block, 512 blocks = 2/CU. Waves share each staged K/V frag
// across 2 row-tiles -> LDS reads per unit work HALVED vs attn10.
// Static kt unroll + wave-uniform predicate (rule #20). K+V double-buffered,
// one barrier/step, race-free. Partials (unnorm bf16 O + m,l) -> combine.
// ---------------------------------------------------------------------------
__global__ __launch_bounds__(256) void attn11(
    const short* __restrict__ Qh, const short* __restrict__ Kh,
    const short* __restrict__ Vt, short* __restrict__ Opart,
    float2* __restrict__ ML)
{
    __shared__ __align__(16) short Kls[2][64 * 128];   // 32 KB
    __shared__ __align__(16) short Vls[2][128 * 64];   // 32 KB

    const int t = threadIdx.x, lane = t & 63, w = t >> 6;
    const int lr = lane & 15, lg = lane >> 4;

    const int g  = blockIdx.x;        // 0..511
    const int bn = g & 31;            // head; bn%8 == g%8 (XCD affinity)
    const int pp = (g >> 5) & 7;
    const int sp = g >> 8;            // step-split 0/1

    const short* Qb = Qh + (size_t)bn * SEQ * HDIM;
    const short* Kb = Kh + (size_t)bn * SEQ * HDIM;
    const short* Vb = Vt + (size_t)bn * HDIM * SEQ;

    auto stageK = [&](int buf, int k0) {
        #pragma unroll
        for (int i = 0; i < 4; ++i) {
            const int q = w * 4 + i;
            const int rowK = q * 4 + (lane >> 4);
            const short* src = Kb + (size_t)(k0 + rowK) * 128 + (((lane & 15) ^ (rowK & 7)) * 8);
            __builtin_amdgcn_global_load_lds(
                (const __attribute__((address_space(1))) unsigned int*)src,
                (__attribute__((address_space(3))) unsigned int*)&Kls[buf][q * 512 + lane * 8],
                16, 0, 0);
        }
    };
    auto stageV = [&](int buf, int k0) {
        #pragma unroll
        for (int i = 0; i < 4; ++i) {
            const int q = w * 4 + i;
            const int d = q * 8 + (lane >> 3);
            const short* src = Vb + (size_t)d * SEQ + k0 + (((lane & 7) ^ (d & 7)) * 8);
            __builtin_amdgcn_global_load_lds(
                (const __attribute__((address_space(1))) unsigned int*)src,
                (__attribute__((address_space(3))) unsigned int*)&Vls[buf][q * 512 + lane * 8],
                16, 0, 0);
        }
    };

    const int sw = lr & 7;
    const bool hi16 = (lg & 1);

    #pragma unroll 1
    for (int phase = 0; phase < 2; ++phase) {
        const int tile = phase ? pp : (15 - pp);
        const int sbeg = sp ? (tile + 1) : 0;
        const int send = sp ? (2 * tile + 2) : (tile + 1);   // t+1 steps either way
        const int q0   = tile * 128 + w * 32;                // wave's first q row

        bfrag qf[2][4];
        #pragma unroll
        for (int rt = 0; rt < 2; ++rt)
            #pragma unroll
            for (int c = 0; c < 4; ++c)
                qf[rt][c] = *(const bfrag*)(Qb + (size_t)(q0 + rt * 16 + lr) * 128 + c * 32 + lg * 8);

        float mcs[2] = {-1.0e30f, -1.0e30f};
        float l[2] = {0.f, 0.f};
        f32x4 o[2][8];
        #pragma unroll
        for (int rt = 0; rt < 2; ++rt)
            #pragma unroll
            for (int dt = 0; dt < 8; ++dt) o[rt][dt] = z4();

        stageV(0, sbeg * 64);
        stageK(0, sbeg * 64);
        __syncthreads();

        for (int s = sbeg; s < send; ++s) {
            const int cur = (s - sbeg) & 1;
            const int k0 = s * 64;
            if (s + 1 < send) { stageV(cur ^ 1, k0 + 64); stageK(cur ^ 1, k0 + 64); }

            // per-wave static masked-subtile bound (wave-uniform)
            int ktend = ((q0 + 31 - k0) >> 4) + 1;
            ktend = ktend < 0 ? 0 : (ktend > 4 ? 4 : ktend);

            // ---- swapped QK^T (static kt unroll, wave-uniform predicate)
            f32x4 sA[2][4];
            #pragma unroll
            for (int rt = 0; rt < 2; ++rt)
                #pragma unroll
                for (int kt = 0; kt < 4; ++kt) sA[rt][kt] = z4();
            __builtin_amdgcn_s_setprio(1);
            #pragma unroll
            for (int kt = 0; kt < 4; ++kt) {
                if (kt < ktend) {   // wave-uniform
                    const char* kbase = (const char*)&Kls[cur][0] + (kt * 16 + lr) * 256;
                    #pragma unroll
                    for (int c = 0; c < 4; ++c) {
                        bfrag kb = *(const bfrag*)(kbase + (((c * 4 + lg) ^ sw) * 16));
                        sA[0][kt] = mfma16(kb, qf[0][c], sA[0][kt]);
                        sA[1][kt] = mfma16(kb, qf[1][c], sA[1][kt]);
                    }
                }
            }
            __builtin_amdgcn_s_setprio(0);

            // ---- causal mask (near-diagonal only)
            if (k0 + 63 > q0) {
                #pragma unroll
                for (int rt = 0; rt < 2; ++rt)
                    #pragma unroll
                    for (int kt = 0; kt < 4; ++kt)
                        #pragma unroll
                        for (int j = 0; j < 4; ++j)
                            if (k0 + kt * 16 + lg * 4 + j > q0 + rt * 16 + lr)
                                sA[rt][kt][j] = -3.0e38f;
            }

            // ---- row max per rt (lane-local row) + T13 defer-rescale
            float pmx[2];
            #pragma unroll
            for (int rt = 0; rt < 2; ++rt) {
                float mx = fmaxf(fmaxf(sA[rt][0][0], sA[rt][0][1]),
                                 fmaxf(sA[rt][0][2], sA[rt][0][3]));
                #pragma unroll
                for (int kt = 1; kt < 4; ++kt)
                    mx = fmaxf(mx, fmaxf(fmaxf(sA[rt][kt][0], sA[rt][kt][1]),
                                         fmaxf(sA[rt][kt][2], sA[rt][kt][3])));
                mx = fmaxf(mx, __shfl_xor(mx, 16));
                mx = fmaxf(mx, __shfl_xor(mx, 32));
                pmx[rt] = mx * CS;
            }
            bool need = (pmx[0] > mcs[0] + 8.0f) || (pmx[1] > mcs[1] + 8.0f);
            if (__any(need ? 1 : 0)) {
                #pragma unroll
                for (int rt = 0; rt < 2; ++rt) {
                    float nm = fmaxf(mcs[rt], pmx[rt]);
                    float al = exp2f(mcs[rt] - nm);
                    mcs[rt] = nm;
                    l[rt] *= al;
                    float alj[4];
                    #pragma unroll
                    for (int j = 0; j < 4; ++j) alj[j] = __shfl(al, lg * 4 + j);
                    #pragma unroll
                    for (int dt = 0; dt < 8; ++dt)
                        #pragma unroll
                        for (int j = 0; j < 4; ++j) o[rt][dt][j] *= alj[j];
                }
            }

            // ---- P = exp2(S*CS - mcs) + lane-local l-sum + in-reg redistribute
            bfrag pa0[2], pa1[2];
            #pragma unroll
            for (int rt = 0; rt < 2; ++rt) {
                float p[4][4];
                float ls = 0.f;
                #pragma unroll
                for (int kt = 0; kt < 4; ++kt)
                    #pragma unroll
                    for (int j = 0; j < 4; ++j) {
                        p[kt][j] = exp2f(sA[rt][kt][j] * CS - mcs[rt]);
                        ls += p[kt][j];
                    }
                ls += __shfl_xor(ls, 16);
                ls += __shfl_xor(ls, 32);
                l[rt] += ls;
                redist(p, hi16, pa0[rt], pa1[rt]);
            }

            // ---- PV from Vls[cur]; each V frag feeds BOTH row-tiles
            __builtin_amdgcn_s_setprio(1);
            #pragma unroll
            for (int dt = 0; dt < 8; ++dt) {
                const char* vbase = (const char*)&Vls[cur][0] + (dt * 16 + lr) * 128;
                bfrag vb0 = *(const bfrag*)(vbase + ((lg ^ sw) * 16));
                bfrag vb1 = *(const bfrag*)(vbase + (((4 + lg) ^ sw) * 16));
                #pragma unroll
                for (int rt = 0; rt < 2; ++rt) {
                    o[rt][dt] = mfma16(pa0[rt], vb0, o[rt][dt]);
                    o[rt][dt] = mfma16(pa1[rt], vb1, o[rt][dt]);
                }
            }
            __builtin_amdgcn_s_setprio(0);

            __syncthreads();   // drains next-step loads; frees cur
        }

        // ---- partial epilogue: unnormalized bf16 O + (m,l) per row
        short* OpW = Opart + ((size_t)sp * NROWS + (size_t)bn * SEQ) * 128;
        float2* MLW = ML + (size_t)sp * NROWS + (size_t)bn * SEQ;
        #pragma unroll
        for (int rt = 0; rt < 2; ++rt) {
            float m4[4], l4[4];
            #pragma unroll
            for (int j = 0; j < 4; ++j) {
                m4[j] = __shfl(mcs[rt], lg * 4 + j);
                l4[j] = __shfl(l[rt],  lg * 4 + j);
            }
            #pragma unroll
            for (int j = 0; j < 4; ++j) {
                int row = q0 + rt * 16 + lg * 4 + j;
                #pragma unroll
                for (int dt = 0; dt < 8; ++dt)
                    OpW[(size_t)row * 128 + dt * 16 + lr] = f2bf(o[rt][dt][j]);
                if (lr == 0)
                    MLW[row] = make_float2(m4[j], l4[j]);
            }
        }
    }
}

// ---------------------------------------------------------------------------
// combine: merge the two step-split partials, normalize, permuted scatter.
// ---------------------------------------------------------------------------
__global__ __launch_bounds__(256) void combine(
    const short* __restrict__ Op, const float2* __restrict__ ML,
    short* __restrict__ Y)
{
    const int idx = blockIdx.x * 256 + threadIdx.x;   // 1,048,576 threads
    const int row = idx >> 4;                          // 0..65535
    const int c0  = (idx & 15) * 8;

    float2 ml0 = ML[row];
    float2 ml1 = ML[NROWS + row];
    float m  = fmaxf(ml0.x, ml1.x);
    float w0 = exp2f(ml0.x - m), w1 = exp2f(ml1.x - m);
    float inv = 1.0f / (ml0.y * w0 + ml1.y * w1);

    const short* p0 = Op + (size_t)row * 128 + c0;
    const short* p1 = Op + (size_t)NROWS * 128 + (size_t)row * 128 + c0;
    s16x4 a0 = *(const s16x4*)p0, a1 = *(const s16x4*)(p0 + 4);
    s16x4 b0 = *(const s16x4*)p1, b1 = *(const s16x4*)(p1 + 4);

    union { s16x4 v[2]; int4 u; } outv;
    #pragma unroll
    for (int i = 0; i < 4; ++i)
        outv.v[0][i] = f2bf((bf2f(a0[i]) * w0 + bf2f(b0[i]) * w1) * inv);
    #pragma unroll
    for (int i = 0; i < 4; ++i)
        outv.v[1][i] = f2bf((bf2f(a1[i]) * w0 + bf2f(b1[i]) * w1) * inv);

    const int bn = row >> 11, q = row & 2047;
    const int b = bn >> 3, n = bn & 7;
    size_t yrow = (size_t)b * SEQ + n * 256 + (q >> 3);
    short* yp = Y + yrow * YN + (q & 7) * 128 + c0;
    *(int4*)yp = outv.u;
}

// ---------------------------------------------------------------------------
// GEMM2: out[8192][128] (f32) = Yb[8192][1024](bf16) @ proj, B as projT[h][k].
// ---------------------------------------------------------------------------
__global__ __launch_bounds__(128) void gemm_out(
    const short* __restrict__ Yb, const short* __restrict__ projT, float* __restrict__ out)
{
    const int t = threadIdx.x, lane = t & 63, w = t >> 6;   // w in 0..1
    const int lr = lane & 15, lg = lane >> 4;
    const int m0 = blockIdx.x * 16;
    const int n0 = w * 64;

    f32x4 acc[4];
    #pragma unroll
    for (int j = 0; j < 4; ++j) acc[j] = z4();

    for (int c = 0; c < 32; ++c) {
        bfrag a = *(const bfrag*)(Yb + (size_t)(m0 + lr) * YN + c * 32 + lg * 8);
        #pragma unroll
        for (int nt = 0; nt < 4; ++nt) {
            bfrag bb = *(const bfrag*)(projT + (size_t)(n0 + nt * 16 + lr) * YN + c * 32 + lg * 8);
            acc[nt] = mfma16(a, bb, acc[nt]);
        }
    }
    #pragma unroll
    for (int nt = 0; nt < 4; ++nt)
        #pragma unroll
        for (int j = 0; j < 4; ++j)
            out[(size_t)(m0 + lg * 4 + j) * HDIM + n0 + nt * 16 + lr] = acc[nt][j];
}

// ---------------------------------------------------------------------------
extern "C" void kernel_launch(void* const* d_in, const int* in_sizes, int n_in,
                              void* d_out, int out_size, void* d_ws, size_t ws_size,
                              hipStream_t stream)
{
    const float* x    = (const float*)d_in[0];  // [4,2048,128]
    const float* qkv  = (const float*)d_in[1];  // [128,3072]
    const float* proj = (const float*)d_in[2];  // [1024,128]
    float* out = (float*)d_out;                 // [8192,128]

    const size_t HEADSZ = (size_t)32 * SEQ * HDIM;        // 8,388,608 elements

    short* XB    = (short*)d_ws;                          // 2 MB
    short* qkvT  = XB    + (size_t)MROWS * HDIM;
    short* projT = qkvT  + (size_t)QKVN * HDIM;
    short* Qh    = projT + (size_t)HDIM * YN;             // 16 MB
    short* Kh    = Qh    + HEADSZ;                        // 16 MB
    short* Vh    = Kh    + HEADSZ;                        // 16 MB
    short* Vtb   = Vh    + HEADSZ;                        // 16 MB
    short* Yb    = Vtb   + HEADSZ;                        // 16 MB
    short* Opart = Yb    + HEADSZ;                        // 2 x 16 MB partials
    float2* ML   = (float2*)(Opart + 2 * HEADSZ);         // 1 MB
    // total ~116 MB

    conv_x    <<<MROWS * HDIM / 1024, 256, 0, stream>>>(x, XB);
    conv_qkvT <<<QKVN * HDIM / 256,  256, 0, stream>>>(qkv, qkvT);
    conv_projT<<<HDIM * YN / 256,    256, 0, stream>>>(proj, projT);

    gemm_qkv<<<dim3(MROWS / 128, QKVN / 128), 256, 0, stream>>>(XB, qkvT, Qh, Kh, Vh);
    transp_v<<<dim3(SEQ / 64, HDIM / 64, 32), 256, 0, stream>>>(Vh, Vtb);
    attn11  <<<512, 256, 0, stream>>>(Qh, Kh, Vtb, Opart, ML);
    combine <<<NROWS * 16 / 256, 256, 0, stream>>>(Opart, ML, Yb);
    gemm_out<<<MROWS / 16, 128, 0, stream>>>(Yb, projT, out);
}

// Round 15
// 185.538 us; speedup vs baseline: 1.0169x; 1.0169x over previous
//
#include <hip/hip_runtime.h>
#include <math.h>

// Problem constants
#define BATCH 4
#define SEQ   2048
#define HDIM  128
#define NHEAD 8
#define MROWS (BATCH*SEQ)    // 8192
#define QKVN  (3*NHEAD*HDIM) // 3072
#define YN    (NHEAD*HDIM)   // 1024

#define CS 0.12751744f   // (1/sqrt(128)) * log2(e)

using bfrag = __attribute__((ext_vector_type(8))) short;  // 8 bf16 (4 VGPRs)
using f32x4 = __attribute__((ext_vector_type(4))) float;
using s16x4 = __attribute__((ext_vector_type(4))) short;

__device__ __forceinline__ f32x4 mfma16(bfrag a, bfrag b, f32x4 c) {
    return __builtin_amdgcn_mfma_f32_16x16x32_bf16(a, b, c, 0, 0, 0);
}
__device__ __forceinline__ short f2bf(float f) {
    union { float f; unsigned u; } v; v.f = f;
    unsigned r = v.u + 0x7FFFu + ((v.u >> 16) & 1u);  // RNE
    return (short)(r >> 16);
}
__device__ __forceinline__ unsigned cvtpk(float lo, float hi) {
    unsigned r;
    asm("v_cvt_pk_bf16_f32 %0, %1, %2" : "=v"(r) : "v"(lo), "v"(hi));
    return r;
}
__device__ __forceinline__ void perm32swap(unsigned &x, unsigned &y) {
    asm volatile("v_permlane32_swap_b32 %0, %1" : "+v"(x), "+v"(y));
}
__device__ __forceinline__ f32x4 z4() { f32x4 z; z[0]=0.f; z[1]=0.f; z[2]=0.f; z[3]=0.f; return z; }

// In-register P redistribution (C-layout -> A-frag layout), validated attn8/10.
__device__ __forceinline__ void redist(const float p[4][4], bool hi16,
                                       bfrag &pa0o, bfrag &pa1o) {
    unsigned pk0[2], pk1[2], pk2[2], pk3[2];
    pk0[0] = cvtpk(p[0][0], p[0][1]); pk0[1] = cvtpk(p[0][2], p[0][3]);
    pk1[0] = cvtpk(p[1][0], p[1][1]); pk1[1] = cvtpk(p[1][2], p[1][3]);
    pk2[0] = cvtpk(p[2][0], p[2][1]); pk2[1] = cvtpk(p[2][2], p[2][3]);
    pk3[0] = cvtpk(p[3][0], p[3][1]); pk3[1] = cvtpk(p[3][2], p[3][3]);
    uint4 w0, w1;
    {
        unsigned A = pk0[0], C = pk1[0];
        perm32swap(A, C);
        unsigned A16 = __shfl_xor((int)A, 16), C16 = __shfl_xor((int)C, 16);
        w0.x = hi16 ? C16 : A;
        w0.z = hi16 ? C   : A16;
        unsigned B = pk0[1], D = pk1[1];
        perm32swap(B, D);
        unsigned B16 = __shfl_xor((int)B, 16), D16 = __shfl_xor((int)D, 16);
        w0.y = hi16 ? D16 : B;
        w0.w = hi16 ? D   : B16;
    }
    {
        unsigned E = pk2[0], G = pk3[0];
        perm32swap(E, G);
        unsigned E16 = __shfl_xor((int)E, 16), G16 = __shfl_xor((int)G, 16);
        w1.x = hi16 ? G16 : E;
        w1.z = hi16 ? G   : E16;
        unsigned F = pk2[1], H = pk3[1];
        perm32swap(F, H);
        unsigned F16 = __shfl_xor((int)F, 16), H16 = __shfl_xor((int)H, 16);
        w1.y = hi16 ? H16 : F;
        w1.w = hi16 ? H   : F16;
    }
    union { uint4 u; bfrag f; } cv0, cv1;
    cv0.u = w0; cv1.u = w1;
    pa0o = cv0.f; pa1o = cv1.f;
}

// ---------------------------------------------------------------------------
// Converters (x conversion is fused into gemm_qkv now)
// ---------------------------------------------------------------------------
__global__ __launch_bounds__(256) void conv_qkvT(const float* __restrict__ q, short* __restrict__ qT) {
    int t = blockIdx.x * 256 + threadIdx.x;         // 3072*128
    int n = t >> 7, k = t & 127;
    qT[t] = f2bf(q[(size_t)k * QKVN + n]);
}
__global__ __launch_bounds__(256) void conv_projT(const float* __restrict__ p, short* __restrict__ pT) {
    int t = blockIdx.x * 256 + threadIdx.x;         // 128*1024
    int h = t >> 10, r = t & 1023;
    pT[t] = f2bf(p[(size_t)r * HDIM + h]);
}

// ---------------------------------------------------------------------------
// GEMM1 (fused x-convert + V-transpose): x(f32) @ qkv, scattered into
//   Qh/Kh[(b*8+n)*2048 + s2][h]   and   Vt[(b*8+n)*128 + h][s2]
// V's column-scatter (stride 4 KB) merges in L2: the 8 partner blocks
// (c8=0..7) filling each 16B span are 64 apart in linear id -> same XCD.
// ---------------------------------------------------------------------------
__global__ __launch_bounds__(256) void gemm_qkv(
    const float* __restrict__ x, const short* __restrict__ qkvT,
    short* __restrict__ Qh, short* __restrict__ Kh, short* __restrict__ Vt)
{
    const int t = threadIdx.x, lane = t & 63, w = t >> 6;
    const int lr = lane & 15, lg = lane >> 4;
    const int m0 = blockIdx.x * 128 + (w >> 1) * 64;
    const int n0 = blockIdx.y * 128 + (w & 1) * 64;

    f32x4 acc[4][4];
    #pragma unroll
    for (int i = 0; i < 4; ++i)
        #pragma unroll
        for (int j = 0; j < 4; ++j) acc[i][j] = z4();

    #pragma unroll
    for (int c = 0; c < 4; ++c) {
        bfrag a[4], bb[4];
        #pragma unroll
        for (int rt = 0; rt < 4; ++rt) {
            const float* xp = x + (size_t)(m0 + rt * 16 + lr) * 128 + c * 32 + lg * 8;
            float4 v0 = *(const float4*)xp;
            float4 v1 = *(const float4*)(xp + 4);
            a[rt][0] = f2bf(v0.x); a[rt][1] = f2bf(v0.y);
            a[rt][2] = f2bf(v0.z); a[rt][3] = f2bf(v0.w);
            a[rt][4] = f2bf(v1.x); a[rt][5] = f2bf(v1.y);
            a[rt][6] = f2bf(v1.z); a[rt][7] = f2bf(v1.w);
        }
        #pragma unroll
        for (int nt = 0; nt < 4; ++nt)
            bb[nt] = *(const bfrag*)(qkvT + (size_t)(n0 + nt * 16 + lr) * 128 + c * 32 + lg * 8);
        #pragma unroll
        for (int rt = 0; rt < 4; ++rt)
            #pragma unroll
            for (int nt = 0; nt < 4; ++nt)
                acc[rt][nt] = mfma16(a[rt], bb[nt], acc[rt][nt]);
    }

    const int part = blockIdx.y >> 3, c8 = blockIdx.y & 7;
    if (part < 2) {
        short* dst = part ? Kh : Qh;
        #pragma unroll
        for (int rt = 0; rt < 4; ++rt)
            #pragma unroll
            for (int j = 0; j < 4; ++j) {
                int r = m0 + rt * 16 + lg * 4 + j;
                int b = r >> 11, sl = r & 2047;
                int n = sl >> 8, s2 = (sl & 255) * 8 + c8;
                size_t rowbase = ((size_t)((b * 8 + n) * 2048 + s2)) * 128;
                #pragma unroll
                for (int nt = 0; nt < 4; ++nt) {
                    int h = (w & 1) * 64 + nt * 16 + lr;
                    dst[rowbase + h] = f2bf(acc[rt][nt][j]);
                }
            }
    } else {
        // V: write transposed -> Vt[(b*8+n)*128 + h][s2]
        #pragma unroll
        for (int rt = 0; rt < 4; ++rt)
            #pragma unroll
            for (int j = 0; j < 4; ++j) {
                int r = m0 + rt * 16 + lg * 4 + j;
                int b = r >> 11, sl = r & 2047;
                int n = sl >> 8, s2 = (sl & 255) * 8 + c8;
                size_t base = ((size_t)((b * 8 + n) * 128)) * 2048 + s2;
                #pragma unroll
                for (int nt = 0; nt < 4; ++nt) {
                    int h = (w & 1) * 64 + nt * 16 + lr;
                    Vt[base + (size_t)h * 2048] = f2bf(acc[rt][nt][j]);
                }
            }
    }
}

// ---------------------------------------------------------------------------
// attn10 (UNCHANGED from round 13 — best measured: 83.4 us):
// 16 q-rows/wave, QBLK=64, tile-pairing (pp, 31-pp) -> 33 uniform steps,
// XCD affinity, K+V double-buffered global_load_lds staging, one barrier
// per step, static kt unroll + wave-uniform predicate, swapped QK^T
// in-register softmax, in-reg P redistribution, T13 defer-rescale.
// ---------------------------------------------------------------------------
__global__ __launch_bounds__(256) void attn10(
    const short* __restrict__ Qh, const short* __restrict__ Kh,
    const short* __restrict__ Vt, short* __restrict__ Y)
{
    __shared__ __align__(16) short Kls[2][64 * 128];   // 32 KB
    __shared__ __align__(16) short Vls[2][128 * 64];   // 32 KB

    const int t = threadIdx.x, lane = t & 63, w = t >> 6;
    const int lr = lane & 15, lg = lane >> 4;

    const int g  = blockIdx.x;        // 0..511
    const int bn = g & 31;            // head id; bn%8 == g%8 (XCD affinity)
    const int pp = g >> 5;            // pair id 0..15 -> tiles (pp, 31-pp)
    const int b  = bn >> 3, n = bn & 7;

    const short* Qb = Qh + (size_t)bn * SEQ * HDIM;
    const short* Kb = Kh + (size_t)bn * SEQ * HDIM;
    const short* Vb = Vt + (size_t)bn * HDIM * SEQ;

    auto stageK = [&](int buf, int k0) {
        #pragma unroll
        for (int i = 0; i < 4; ++i) {
            const int q = w * 4 + i;
            const int rowK = q * 4 + (lane >> 4);
            const short* src = Kb + (size_t)(k0 + rowK) * 128 + (((lane & 15) ^ (rowK & 7)) * 8);
            __builtin_amdgcn_global_load_lds(
                (const __attribute__((address_space(1))) unsigned int*)src,
                (__attribute__((address_space(3))) unsigned int*)&Kls[buf][q * 512 + lane * 8],
                16, 0, 0);
        }
    };
    auto stageV = [&](int buf, int k0) {
        #pragma unroll
        for (int i = 0; i < 4; ++i) {
            const int q = w * 4 + i;
            const int d = q * 8 + (lane >> 3);
            const short* src = Vb + (size_t)d * SEQ + k0 + (((lane & 7) ^ (d & 7)) * 8);
            __builtin_amdgcn_global_load_lds(
                (const __attribute__((address_space(1))) unsigned int*)src,
                (__attribute__((address_space(3))) unsigned int*)&Vls[buf][q * 512 + lane * 8],
                16, 0, 0);
        }
    };

    const int sw = lr & 7;
    const bool hi16 = (lg & 1);

    #pragma unroll 1
    for (int phase = 0; phase < 2; ++phase) {
        const int tile = phase ? pp : (31 - pp);    // long tile first
        const int q0 = tile * 64 + w * 16;

        bfrag qf[4];
        #pragma unroll
        for (int c = 0; c < 4; ++c)
            qf[c] = *(const bfrag*)(Qb + (size_t)(q0 + lr) * 128 + c * 32 + lg * 8);

        float mcs = -1.0e30f, l = 0.f;              // per-lane: q = q0 + lr
        f32x4 o[8];
        #pragma unroll
        for (int dt = 0; dt < 8; ++dt) o[dt] = z4();

        stageV(0, 0);
        stageK(0, 0);
        __syncthreads();   // buffer 0 staged

        for (int s = 0; s <= tile; ++s) {
            const int cur = s & 1;
            const int k0 = s * 64;
            if (s < tile) { stageV(cur ^ 1, k0 + 64); stageK(cur ^ 1, k0 + 64); }

            f32x4 sA[4];
            #pragma unroll
            for (int kt = 0; kt < 4; ++kt) sA[kt] = z4();
            const int ktend = (s == tile) ? (w + 1) : 4;
            __builtin_amdgcn_s_setprio(1);
            #pragma unroll
            for (int kt = 0; kt < 4; ++kt) {
                if (kt < ktend) {   // wave-uniform
                    const char* kbase = (const char*)&Kls[cur][0] + (kt * 16 + lr) * 256;
                    #pragma unroll
                    for (int c = 0; c < 4; ++c) {
                        bfrag kb = *(const bfrag*)(kbase + (((c * 4 + lg) ^ sw) * 16));
                        sA[kt] = mfma16(kb, qf[c], sA[kt]);   // swapped operands
                    }
                }
            }
            __builtin_amdgcn_s_setprio(0);

            if (s == tile) {
                #pragma unroll
                for (int kt = 0; kt < 4; ++kt)
                    #pragma unroll
                    for (int j = 0; j < 4; ++j)
                        if (kt * 16 + lg * 4 + j > w * 16 + lr)
                            sA[kt][j] = -3.0e38f;
            }

            float mx = fmaxf(fmaxf(sA[0][0], sA[0][1]), fmaxf(sA[0][2], sA[0][3]));
            #pragma unroll
            for (int kt = 1; kt < 4; ++kt)
                mx = fmaxf(mx, fmaxf(fmaxf(sA[kt][0], sA[kt][1]),
                                     fmaxf(sA[kt][2], sA[kt][3])));
            mx = fmaxf(mx, __shfl_xor(mx, 16));
            mx = fmaxf(mx, __shfl_xor(mx, 32));
            const float pmx = mx * CS;

            if (__any((pmx > mcs + 8.0f) ? 1 : 0)) {
                float nm = fmaxf(mcs, pmx);
                float al = exp2f(mcs - nm);
                mcs = nm;
                l *= al;
                float alj[4];
                #pragma unroll
                for (int j = 0; j < 4; ++j) alj[j] = __shfl(al, lg * 4 + j);
                #pragma unroll
                for (int dt = 0; dt < 8; ++dt)
                    #pragma unroll
                    for (int j = 0; j < 4; ++j) o[dt][j] *= alj[j];
            }

            float p[4][4];
            float ls = 0.f;
            #pragma unroll
            for (int kt = 0; kt < 4; ++kt)
                #pragma unroll
                for (int j = 0; j < 4; ++j) {
                    p[kt][j] = exp2f(sA[kt][j] * CS - mcs);
                    ls += p[kt][j];
                }
            ls += __shfl_xor(ls, 16);
            ls += __shfl_xor(ls, 32);
            l += ls;

            bfrag pa0, pa1;
            redist(p, hi16, pa0, pa1);

            __builtin_amdgcn_s_setprio(1);
            #pragma unroll
            for (int dt = 0; dt < 8; ++dt) {
                const char* vbase = (const char*)&Vls[cur][0] + (dt * 16 + lr) * 128;
                bfrag vb0 = *(const bfrag*)(vbase + ((lg ^ sw) * 16));
                bfrag vb1 = *(const bfrag*)(vbase + (((4 + lg) ^ sw) * 16));
                o[dt] = mfma16(pa0, vb0, o[dt]);
                o[dt] = mfma16(pa1, vb1, o[dt]);
            }
            __builtin_amdgcn_s_setprio(0);

            __syncthreads();
        }

        float inv[4];
        #pragma unroll
        for (int j = 0; j < 4; ++j) inv[j] = 1.0f / __shfl(l, lg * 4 + j);
        #pragma unroll
        for (int j = 0; j < 4; ++j) {
            int s2 = q0 + lg * 4 + j;
            size_t yrow = (size_t)b * SEQ + n * 256 + (s2 >> 3);
            short* yp = Y + yrow * YN + (s2 & 7) * 128 + lr;
            #pragma unroll
            for (int dt = 0; dt < 8; ++dt)
                yp[dt * 16] = f2bf(o[dt][j] * inv[j]);
        }
    }
}

// ---------------------------------------------------------------------------
// GEMM2: out[8192][128] (f32) = Yb[8192][1024](bf16) @ proj, B as projT[h][k].
// 4 waves/block, each 16 rows x 32 cols -> light waves (VGPR ~40), 2048 waves
// total for latency hiding on this memory-bound epilogue.
// ---------------------------------------------------------------------------
__global__ __launch_bounds__(256) void gemm_out(
    const short* __restrict__ Yb, const short* __restrict__ projT, float* __restrict__ out)
{
    const int t = threadIdx.x, lane = t & 63, w = t >> 6;   // w in 0..3
    const int lr = lane & 15, lg = lane >> 4;
    const int m0 = blockIdx.x * 16;
    const int n0 = w * 32;

    f32x4 acc[2] = {z4(), z4()};

    for (int c = 0; c < 32; ++c) {
        bfrag a = *(const bfrag*)(Yb + (size_t)(m0 + lr) * YN + c * 32 + lg * 8);
        #pragma unroll
        for (int nt = 0; nt < 2; ++nt) {
            bfrag bb = *(const bfrag*)(projT + (size_t)(n0 + nt * 16 + lr) * YN + c * 32 + lg * 8);
            acc[nt] = mfma16(a, bb, acc[nt]);
        }
    }
    #pragma unroll
    for (int nt = 0; nt < 2; ++nt)
        #pragma unroll
        for (int j = 0; j < 4; ++j)
            out[(size_t)(m0 + lg * 4 + j) * HDIM + n0 + nt * 16 + lr] = acc[nt][j];
}

// ---------------------------------------------------------------------------
extern "C" void kernel_launch(void* const* d_in, const int* in_sizes, int n_in,
                              void* d_out, int out_size, void* d_ws, size_t ws_size,
                              hipStream_t stream)
{
    const float* x    = (const float*)d_in[0];  // [4,2048,128]
    const float* qkv  = (const float*)d_in[1];  // [128,3072]
    const float* proj = (const float*)d_in[2];  // [1024,128]
    float* out = (float*)d_out;                 // [8192,128]

    const size_t HEADSZ = (size_t)32 * SEQ * HDIM;        // 8,388,608 elements

    short* qkvT  = (short*)d_ws;                          // 0.75 MB
    short* projT = qkvT  + (size_t)QKVN * HDIM;           // 0.25 MB
    short* Qh    = projT + (size_t)HDIM * YN;             // 16 MB
    short* Kh    = Qh    + HEADSZ;                        // 16 MB
    short* Vtb   = Kh    + HEADSZ;                        // 16 MB (transposed V)
    short* Yb    = Vtb   + HEADSZ;                        // 16 MB  (~65 MB total)

    conv_qkvT <<<QKVN * HDIM / 256, 256, 0, stream>>>(qkv, qkvT);
    conv_projT<<<HDIM * YN / 256,   256, 0, stream>>>(proj, projT);

    gemm_qkv<<<dim3(MROWS / 128, QKVN / 128), 256, 0, stream>>>(x, qkvT, Qh, Kh, Vtb);
    attn10  <<<512, 256, 0, stream>>>(Qh, Kh, Vtb, Yb);
    gemm_out<<<MROWS / 16, 256, 0, stream>>>(Yb, projT, out);
}

// Round 16
// 157.240 us; speedup vs baseline: 1.1999x; 1.1800x over previous
//
#include <hip/hip_runtime.h>
#include <math.h>

// Problem constants
#define BATCH 4
#define SEQ   2048
#define HDIM  128
#define NHEAD 8
#define MROWS (BATCH*SEQ)    // 8192
#define QKVN  (3*NHEAD*HDIM) // 3072
#define YN    (NHEAD*HDIM)   // 1024

#define CS 0.12751744f   // (1/sqrt(128)) * log2(e)

using bfrag = __attribute__((ext_vector_type(8))) short;  // 8 bf16 (4 VGPRs)
using f32x4 = __attribute__((ext_vector_type(4))) float;
using s16x4 = __attribute__((ext_vector_type(4))) short;

__device__ __forceinline__ f32x4 mfma16(bfrag a, bfrag b, f32x4 c) {
    return __builtin_amdgcn_mfma_f32_16x16x32_bf16(a, b, c, 0, 0, 0);
}
__device__ __forceinline__ short f2bf(float f) {
    union { float f; unsigned u; } v; v.f = f;
    unsigned r = v.u + 0x7FFFu + ((v.u >> 16) & 1u);  // RNE
    return (short)(r >> 16);
}
__device__ __forceinline__ unsigned cvtpk(float lo, float hi) {
    unsigned r;
    asm("v_cvt_pk_bf16_f32 %0, %1, %2" : "=v"(r) : "v"(lo), "v"(hi));
    return r;   // bits[15:0]=bf16(lo), bits[31:16]=bf16(hi)
}
__device__ __forceinline__ void perm32swap(unsigned &x, unsigned &y) {
    asm volatile("v_permlane32_swap_b32 %0, %1" : "+v"(x), "+v"(y));
}
__device__ __forceinline__ f32x4 z4() { f32x4 z; z[0]=0.f; z[1]=0.f; z[2]=0.f; z[3]=0.f; return z; }

// In-register P redistribution (C-layout -> A-frag layout), validated attn8/10.
__device__ __forceinline__ void redist(const float p[4][4], bool hi16,
                                       bfrag &pa0o, bfrag &pa1o) {
    unsigned pk0[2], pk1[2], pk2[2], pk3[2];
    pk0[0] = cvtpk(p[0][0], p[0][1]); pk0[1] = cvtpk(p[0][2], p[0][3]);
    pk1[0] = cvtpk(p[1][0], p[1][1]); pk1[1] = cvtpk(p[1][2], p[1][3]);
    pk2[0] = cvtpk(p[2][0], p[2][1]); pk2[1] = cvtpk(p[2][2], p[2][3]);
    pk3[0] = cvtpk(p[3][0], p[3][1]); pk3[1] = cvtpk(p[3][2], p[3][3]);
    uint4 w0, w1;
    {
        unsigned A = pk0[0], C = pk1[0];
        perm32swap(A, C);
        unsigned A16 = __shfl_xor((int)A, 16), C16 = __shfl_xor((int)C, 16);
        w0.x = hi16 ? C16 : A;
        w0.z = hi16 ? C   : A16;
        unsigned B = pk0[1], D = pk1[1];
        perm32swap(B, D);
        unsigned B16 = __shfl_xor((int)B, 16), D16 = __shfl_xor((int)D, 16);
        w0.y = hi16 ? D16 : B;
        w0.w = hi16 ? D   : B16;
    }
    {
        unsigned E = pk2[0], G = pk3[0];
        perm32swap(E, G);
        unsigned E16 = __shfl_xor((int)E, 16), G16 = __shfl_xor((int)G, 16);
        w1.x = hi16 ? G16 : E;
        w1.z = hi16 ? G   : E16;
        unsigned F = pk2[1], H = pk3[1];
        perm32swap(F, H);
        unsigned F16 = __shfl_xor((int)F, 16), H16 = __shfl_xor((int)H, 16);
        w1.y = hi16 ? H16 : F;
        w1.w = hi16 ? H   : F16;
    }
    union { uint4 u; bfrag f; } cv0, cv1;
    cv0.u = w0; cv1.u = w1;
    pa0o = cv0.f; pa1o = cv1.f;
}

// ---------------------------------------------------------------------------
// Converters (x conversion fused into gemm_qkv)
// ---------------------------------------------------------------------------
__global__ __launch_bounds__(256) void conv_qkvT(const float* __restrict__ q, short* __restrict__ qT) {
    int t = blockIdx.x * 256 + threadIdx.x;         // 3072*128
    int n = t >> 7, k = t & 127;
    qT[t] = f2bf(q[(size_t)k * QKVN + n]);
}
__global__ __launch_bounds__(256) void conv_projT(const float* __restrict__ p, short* __restrict__ pT) {
    int t = blockIdx.x * 256 + threadIdx.x;         // 128*1024
    int h = t >> 10, r = t & 1023;
    pT[t] = f2bf(p[(size_t)r * HDIM + h]);
}

// ---------------------------------------------------------------------------
// GEMM1 (fused x-convert, SWAPPED-operand C layout): x(f32) @ qkv scattered
// into row-major per-head Qh/Kh/Vh[(b*8+n)*2048 + s2][h].
// mfma16(bb, a, acc) -> thread holds C[m = m0+rt*16+lr][n = n0+nt*16+lg*4+jj]
// = 4 CONSECUTIVE h per thread -> 16 x 8B stores (cvt_pk-packed) instead of
// 64 x 2B scalar stores (round-13) or the round-15 V-column-scatter disaster.
// ---------------------------------------------------------------------------
__global__ __launch_bounds__(256) void gemm_qkv(
    const float* __restrict__ x, const short* __restrict__ qkvT,
    short* __restrict__ Qh, short* __restrict__ Kh, short* __restrict__ Vh)
{
    const int t = threadIdx.x, lane = t & 63, w = t >> 6;
    const int lr = lane & 15, lg = lane >> 4;
    const int m0 = blockIdx.x * 128 + (w >> 1) * 64;
    const int n0 = blockIdx.y * 128 + (w & 1) * 64;

    f32x4 acc[4][4];
    #pragma unroll
    for (int i = 0; i < 4; ++i)
        #pragma unroll
        for (int j = 0; j < 4; ++j) acc[i][j] = z4();

    #pragma unroll
    for (int c = 0; c < 4; ++c) {
        bfrag a[4], bb[4];
        #pragma unroll
        for (int rt = 0; rt < 4; ++rt) {
            const float* xp = x + (size_t)(m0 + rt * 16 + lr) * 128 + c * 32 + lg * 8;
            float4 v0 = *(const float4*)xp;
            float4 v1 = *(const float4*)(xp + 4);
            union { uint4 u; bfrag f; } cv;
            cv.u.x = cvtpk(v0.x, v0.y);
            cv.u.y = cvtpk(v0.z, v0.w);
            cv.u.z = cvtpk(v1.x, v1.y);
            cv.u.w = cvtpk(v1.z, v1.w);
            a[rt] = cv.f;
        }
        #pragma unroll
        for (int nt = 0; nt < 4; ++nt)
            bb[nt] = *(const bfrag*)(qkvT + (size_t)(n0 + nt * 16 + lr) * 128 + c * 32 + lg * 8);
        #pragma unroll
        for (int rt = 0; rt < 4; ++rt)
            #pragma unroll
            for (int nt = 0; nt < 4; ++nt)
                acc[rt][nt] = mfma16(bb[nt], a[rt], acc[rt][nt]);   // SWAPPED
    }

    const int part = blockIdx.y >> 3, c8 = blockIdx.y & 7;
    short* dst = (part == 0) ? Qh : ((part == 1) ? Kh : Vh);
    #pragma unroll
    for (int rt = 0; rt < 4; ++rt) {
        int m = m0 + rt * 16 + lr;
        int b = m >> 11, sl = m & 2047;
        int nh = sl >> 8, s2 = (sl & 255) * 8 + c8;
        size_t rowbase = ((size_t)((b * 8 + nh) * 2048 + s2)) * 128;
        #pragma unroll
        for (int nt = 0; nt < 4; ++nt) {
            int h0 = (w & 1) * 64 + nt * 16 + lg * 4;
            uint2 pk;
            pk.x = cvtpk(acc[rt][nt][0], acc[rt][nt][1]);
            pk.y = cvtpk(acc[rt][nt][2], acc[rt][nt][3]);
            *(uint2*)(dst + rowbase + h0) = pk;
        }
    }
}

// ---------------------------------------------------------------------------
// Transpose V per head: Vh[bn][s2][d] -> Vt[bn][d][s2]. (round-13 verbatim;
// LDS-tiled, coalesced both sides — the r15 fused scatter was 40us slower)
// ---------------------------------------------------------------------------
__global__ __launch_bounds__(256) void transp_v(
    const short* __restrict__ Vh, short* __restrict__ Vt)
{
    __shared__ short Ls[64][72];
    const int bn = blockIdx.z, s20 = blockIdx.x * 64, d0 = blockIdx.y * 64;
    const int t = threadIdx.x;
    const short* src = Vh + ((size_t)bn * SEQ + s20) * 128 + d0;
    {
        int r = t >> 2, ch = (t & 3) * 16;
        *(int4*)&Ls[r][ch]     = *(const int4*)(src + (size_t)r * 128 + ch);
        *(int4*)&Ls[r][ch + 8] = *(const int4*)(src + (size_t)r * 128 + ch + 8);
    }
    __syncthreads();
    {
        int dr = t >> 2, ch = (t & 3) * 16;
        short tmp[16];
        #pragma unroll
        for (int i = 0; i < 16; ++i) tmp[i] = Ls[ch + i][dr];
        short* dp = Vt + ((size_t)bn * HDIM + d0 + dr) * SEQ + s20 + ch;
        *(int4*)dp       = *(int4*)&tmp[0];
        *(int4*)(dp + 8) = *(int4*)&tmp[8];
    }
}

// ---------------------------------------------------------------------------
// attn10 (UNCHANGED — best measured: 83.4 us):
// 16 q-rows/wave, QBLK=64, tile-pairing (pp, 31-pp) -> 33 uniform steps,
// XCD affinity, K+V double-buffered global_load_lds staging, one barrier
// per step, static kt unroll + wave-uniform predicate, swapped QK^T
// in-register softmax, in-reg P redistribution, T13 defer-rescale.
// ---------------------------------------------------------------------------
__global__ __launch_bounds__(256) void attn10(
    const short* __restrict__ Qh, const short* __restrict__ Kh,
    const short* __restrict__ Vt, short* __restrict__ Y)
{
    __shared__ __align__(16) short Kls[2][64 * 128];   // 32 KB
    __shared__ __align__(16) short Vls[2][128 * 64];   // 32 KB

    const int t = threadIdx.x, lane = t & 63, w = t >> 6;
    const int lr = lane & 15, lg = lane >> 4;

    const int g  = blockIdx.x;        // 0..511
    const int bn = g & 31;            // head id; bn%8 == g%8 (XCD affinity)
    const int pp = g >> 5;            // pair id 0..15 -> tiles (pp, 31-pp)
    const int b  = bn >> 3, n = bn & 7;

    const short* Qb = Qh + (size_t)bn * SEQ * HDIM;
    const short* Kb = Kh + (size_t)bn * SEQ * HDIM;
    const short* Vb = Vt + (size_t)bn * HDIM * SEQ;

    auto stageK = [&](int buf, int k0) {
        #pragma unroll
        for (int i = 0; i < 4; ++i) {
            const int q = w * 4 + i;
            const int rowK = q * 4 + (lane >> 4);
            const short* src = Kb + (size_t)(k0 + rowK) * 128 + (((lane & 15) ^ (rowK & 7)) * 8);
            __builtin_amdgcn_global_load_lds(
                (const __attribute__((address_space(1))) unsigned int*)src,
                (__attribute__((address_space(3))) unsigned int*)&Kls[buf][q * 512 + lane * 8],
                16, 0, 0);
        }
    };
    auto stageV = [&](int buf, int k0) {
        #pragma unroll
        for (int i = 0; i < 4; ++i) {
            const int q = w * 4 + i;
            const int d = q * 8 + (lane >> 3);
            const short* src = Vb + (size_t)d * SEQ + k0 + (((lane & 7) ^ (d & 7)) * 8);
            __builtin_amdgcn_global_load_lds(
                (const __attribute__((address_space(1))) unsigned int*)src,
                (__attribute__((address_space(3))) unsigned int*)&Vls[buf][q * 512 + lane * 8],
                16, 0, 0);
        }
    };

    const int sw = lr & 7;
    const bool hi16 = (lg & 1);

    #pragma unroll 1
    for (int phase = 0; phase < 2; ++phase) {
        const int tile = phase ? pp : (31 - pp);    // long tile first
        const int q0 = tile * 64 + w * 16;

        bfrag qf[4];
        #pragma unroll
        for (int c = 0; c < 4; ++c)
            qf[c] = *(const bfrag*)(Qb + (size_t)(q0 + lr) * 128 + c * 32 + lg * 8);

        float mcs = -1.0e30f, l = 0.f;              // per-lane: q = q0 + lr
        f32x4 o[8];
        #pragma unroll
        for (int dt = 0; dt < 8; ++dt) o[dt] = z4();

        stageV(0, 0);
        stageK(0, 0);
        __syncthreads();   // buffer 0 staged

        for (int s = 0; s <= tile; ++s) {
            const int cur = s & 1;
            const int k0 = s * 64;
            if (s < tile) { stageV(cur ^ 1, k0 + 64); stageK(cur ^ 1, k0 + 64); }

            f32x4 sA[4];
            #pragma unroll
            for (int kt = 0; kt < 4; ++kt) sA[kt] = z4();
            const int ktend = (s == tile) ? (w + 1) : 4;
            __builtin_amdgcn_s_setprio(1);
            #pragma unroll
            for (int kt = 0; kt < 4; ++kt) {
                if (kt < ktend) {   // wave-uniform
                    const char* kbase = (const char*)&Kls[cur][0] + (kt * 16 + lr) * 256;
                    #pragma unroll
                    for (int c = 0; c < 4; ++c) {
                        bfrag kb = *(const bfrag*)(kbase + (((c * 4 + lg) ^ sw) * 16));
                        sA[kt] = mfma16(kb, qf[c], sA[kt]);   // swapped operands
                    }
                }
            }
            __builtin_amdgcn_s_setprio(0);

            if (s == tile) {
                #pragma unroll
                for (int kt = 0; kt < 4; ++kt)
                    #pragma unroll
                    for (int j = 0; j < 4; ++j)
                        if (kt * 16 + lg * 4 + j > w * 16 + lr)
                            sA[kt][j] = -3.0e38f;
            }

            float mx = fmaxf(fmaxf(sA[0][0], sA[0][1]), fmaxf(sA[0][2], sA[0][3]));
            #pragma unroll
            for (int kt = 1; kt < 4; ++kt)
                mx = fmaxf(mx, fmaxf(fmaxf(sA[kt][0], sA[kt][1]),
                                     fmaxf(sA[kt][2], sA[kt][3])));
            mx = fmaxf(mx, __shfl_xor(mx, 16));
            mx = fmaxf(mx, __shfl_xor(mx, 32));
            const float pmx = mx * CS;

            if (__any((pmx > mcs + 8.0f) ? 1 : 0)) {
                float nm = fmaxf(mcs, pmx);
                float al = exp2f(mcs - nm);
                mcs = nm;
                l *= al;
                float alj[4];
                #pragma unroll
                for (int j = 0; j < 4; ++j) alj[j] = __shfl(al, lg * 4 + j);
                #pragma unroll
                for (int dt = 0; dt < 8; ++dt)
                    #pragma unroll
                    for (int j = 0; j < 4; ++j) o[dt][j] *= alj[j];
            }

            float p[4][4];
            float ls = 0.f;
            #pragma unroll
            for (int kt = 0; kt < 4; ++kt)
                #pragma unroll
                for (int j = 0; j < 4; ++j) {
                    p[kt][j] = exp2f(sA[kt][j] * CS - mcs);
                    ls += p[kt][j];
                }
            ls += __shfl_xor(ls, 16);
            ls += __shfl_xor(ls, 32);
            l += ls;

            bfrag pa0, pa1;
            redist(p, hi16, pa0, pa1);

            __builtin_amdgcn_s_setprio(1);
            #pragma unroll
            for (int dt = 0; dt < 8; ++dt) {
                const char* vbase = (const char*)&Vls[cur][0] + (dt * 16 + lr) * 128;
                bfrag vb0 = *(const bfrag*)(vbase + ((lg ^ sw) * 16));
                bfrag vb1 = *(const bfrag*)(vbase + (((4 + lg) ^ sw) * 16));
                o[dt] = mfma16(pa0, vb0, o[dt]);
                o[dt] = mfma16(pa1, vb1, o[dt]);
            }
            __builtin_amdgcn_s_setprio(0);

            __syncthreads();
        }

        float inv[4];
        #pragma unroll
        for (int j = 0; j < 4; ++j) inv[j] = 1.0f / __shfl(l, lg * 4 + j);
        #pragma unroll
        for (int j = 0; j < 4; ++j) {
            int s2 = q0 + lg * 4 + j;
            size_t yrow = (size_t)b * SEQ + n * 256 + (s2 >> 3);
            short* yp = Y + yrow * YN + (s2 & 7) * 128 + lr;
            #pragma unroll
            for (int dt = 0; dt < 8; ++dt)
                yp[dt * 16] = f2bf(o[dt][j] * inv[j]);
        }
    }
}

// ---------------------------------------------------------------------------
// GEMM2 (SWAPPED-operand): out[8192][128] (f32) = Yb @ proj, B as projT.
// mfma16(bb, a, acc) -> thread holds out[m = m0+lr][n = n0+nt*16+lg*4+jj]
// -> 4 float4 stores per thread (accumulator stored directly, no convert).
// ---------------------------------------------------------------------------
__global__ __launch_bounds__(128) void gemm_out(
    const short* __restrict__ Yb, const short* __restrict__ projT, float* __restrict__ out)
{
    const int t = threadIdx.x, lane = t & 63, w = t >> 6;   // w in 0..1
    const int lr = lane & 15, lg = lane >> 4;
    const int m0 = blockIdx.x * 16;
    const int n0 = w * 64;

    f32x4 acc[4];
    #pragma unroll
    for (int j = 0; j < 4; ++j) acc[j] = z4();

    for (int c = 0; c < 32; ++c) {
        bfrag a = *(const bfrag*)(Yb + (size_t)(m0 + lr) * YN + c * 32 + lg * 8);
        #pragma unroll
        for (int nt = 0; nt < 4; ++nt) {
            bfrag bb = *(const bfrag*)(projT + (size_t)(n0 + nt * 16 + lr) * YN + c * 32 + lg * 8);
            acc[nt] = mfma16(bb, a, acc[nt]);   // SWAPPED
        }
    }
    #pragma unroll
    for (int nt = 0; nt < 4; ++nt)
        *(f32x4*)(out + (size_t)(m0 + lr) * HDIM + n0 + nt * 16 + lg * 4) = acc[nt];
}

// ---------------------------------------------------------------------------
extern "C" void kernel_launch(void* const* d_in, const int* in_sizes, int n_in,
                              void* d_out, int out_size, void* d_ws, size_t ws_size,
                              hipStream_t stream)
{
    const float* x    = (const float*)d_in[0];  // [4,2048,128]
    const float* qkv  = (const float*)d_in[1];  // [128,3072]
    const float* proj = (const float*)d_in[2];  // [1024,128]
    float* out = (float*)d_out;                 // [8192,128]

    const size_t HEADSZ = (size_t)32 * SEQ * HDIM;        // 8,388,608 elements

    short* qkvT  = (short*)d_ws;                          // 0.75 MB
    short* projT = qkvT  + (size_t)QKVN * HDIM;           // 0.25 MB
    short* Qh    = projT + (size_t)HDIM * YN;             // 16 MB
    short* Kh    = Qh    + HEADSZ;                        // 16 MB
    short* Vh    = Kh    + HEADSZ;                        // 16 MB (row-major)
    short* Vtb   = Vh    + HEADSZ;                        // 16 MB (transposed)
    short* Yb    = Vtb   + HEADSZ;                        // 16 MB  (~81 MB total)

    conv_qkvT <<<QKVN * HDIM / 256, 256, 0, stream>>>(qkv, qkvT);
    conv_projT<<<HDIM * YN / 256,   256, 0, stream>>>(proj, projT);

    gemm_qkv<<<dim3(MROWS / 128, QKVN / 128), 256, 0, stream>>>(x, qkvT, Qh, Kh, Vh);
    transp_v<<<dim3(SEQ / 64, HDIM / 64, 32), 256, 0, stream>>>(Vh, Vtb);
    attn10  <<<512, 256, 0, stream>>>(Qh, Kh, Vtb, Yb);
    gemm_out<<<MROWS / 16, 128, 0, stream>>>(Yb, projT, out);
}

// Round 17
// 148.973 us; speedup vs baseline: 1.2665x; 1.0555x over previous
//
#include <hip/hip_runtime.h>
#include <math.h>

// Problem constants
#define BATCH 4
#define SEQ   2048
#define HDIM  128
#define NHEAD 8
#define MROWS (BATCH*SEQ)    // 8192
#define QKVN  (3*NHEAD*HDIM) // 3072
#define YN    (NHEAD*HDIM)   // 1024

#define CS 0.12751744f   // (1/sqrt(128)) * log2(e)

using bfrag = __attribute__((ext_vector_type(8))) short;  // 8 bf16 (4 VGPRs)
using f32x4 = __attribute__((ext_vector_type(4))) float;
using s16x4 = __attribute__((ext_vector_type(4))) short;

__device__ __forceinline__ f32x4 mfma16(bfrag a, bfrag b, f32x4 c) {
    return __builtin_amdgcn_mfma_f32_16x16x32_bf16(a, b, c, 0, 0, 0);
}
__device__ __forceinline__ short f2bf(float f) {
    union { float f; unsigned u; } v; v.f = f;
    unsigned r = v.u + 0x7FFFu + ((v.u >> 16) & 1u);  // RNE
    return (short)(r >> 16);
}
__device__ __forceinline__ unsigned cvtpk(float lo, float hi) {
    unsigned r;
    asm("v_cvt_pk_bf16_f32 %0, %1, %2" : "=v"(r) : "v"(lo), "v"(hi));
    return r;   // bits[15:0]=bf16(lo), bits[31:16]=bf16(hi)
}
__device__ __forceinline__ void perm32swap(unsigned &x, unsigned &y) {
    asm volatile("v_permlane32_swap_b32 %0, %1" : "+v"(x), "+v"(y));
}
__device__ __forceinline__ f32x4 z4() { f32x4 z; z[0]=0.f; z[1]=0.f; z[2]=0.f; z[3]=0.f; return z; }

// In-register P redistribution (C-layout -> A-frag layout), validated attn8/10.
__device__ __forceinline__ void redist(const float p[4][4], bool hi16,
                                       bfrag &pa0o, bfrag &pa1o) {
    unsigned pk0[2], pk1[2], pk2[2], pk3[2];
    pk0[0] = cvtpk(p[0][0], p[0][1]); pk0[1] = cvtpk(p[0][2], p[0][3]);
    pk1[0] = cvtpk(p[1][0], p[1][1]); pk1[1] = cvtpk(p[1][2], p[1][3]);
    pk2[0] = cvtpk(p[2][0], p[2][1]); pk2[1] = cvtpk(p[2][2], p[2][3]);
    pk3[0] = cvtpk(p[3][0], p[3][1]); pk3[1] = cvtpk(p[3][2], p[3][3]);
    uint4 w0, w1;
    {
        unsigned A = pk0[0], C = pk1[0];
        perm32swap(A, C);
        unsigned A16 = __shfl_xor((int)A, 16), C16 = __shfl_xor((int)C, 16);
        w0.x = hi16 ? C16 : A;
        w0.z = hi16 ? C   : A16;
        unsigned B = pk0[1], D = pk1[1];
        perm32swap(B, D);
        unsigned B16 = __shfl_xor((int)B, 16), D16 = __shfl_xor((int)D, 16);
        w0.y = hi16 ? D16 : B;
        w0.w = hi16 ? D   : B16;
    }
    {
        unsigned E = pk2[0], G = pk3[0];
        perm32swap(E, G);
        unsigned E16 = __shfl_xor((int)E, 16), G16 = __shfl_xor((int)G, 16);
        w1.x = hi16 ? G16 : E;
        w1.z = hi16 ? G   : E16;
        unsigned F = pk2[1], H = pk3[1];
        perm32swap(F, H);
        unsigned F16 = __shfl_xor((int)F, 16), H16 = __shfl_xor((int)H, 16);
        w1.y = hi16 ? H16 : F;
        w1.w = hi16 ? H   : F16;
    }
    union { uint4 u; bfrag f; } cv0, cv1;
    cv0.u = w0; cv1.u = w1;
    pa0o = cv0.f; pa1o = cv1.f;
}

// ---------------------------------------------------------------------------
// Converters (round-13 structure restored: separate conv_x, bf16 XB)
// ---------------------------------------------------------------------------
__global__ __launch_bounds__(256) void conv_x(const float* __restrict__ x, short* __restrict__ XB) {
    int i = (blockIdx.x * 256 + threadIdx.x) * 4;
    float4 v = *(const float4*)(x + i);
    s16x4 o; o[0] = f2bf(v.x); o[1] = f2bf(v.y); o[2] = f2bf(v.z); o[3] = f2bf(v.w);
    *(s16x4*)(XB + i) = o;
}
__global__ __launch_bounds__(256) void conv_qkvT(const float* __restrict__ q, short* __restrict__ qT) {
    int t = blockIdx.x * 256 + threadIdx.x;         // 3072*128
    int n = t >> 7, k = t & 127;
    qT[t] = f2bf(q[(size_t)k * QKVN + n]);
}
__global__ __launch_bounds__(256) void conv_projT(const float* __restrict__ p, short* __restrict__ pT) {
    int t = blockIdx.x * 256 + threadIdx.x;         // 128*1024
    int h = t >> 10, r = t & 1023;
    pT[t] = f2bf(p[(size_t)r * HDIM + h]);
}

// ---------------------------------------------------------------------------
// GEMM1 (round-13 skeleton + SWAPPED-operand packed stores only):
// XB(bf16) @ qkv -> per-head Qh/Kh/Vh[(b*8+n)*2048 + s2][h].
// mfma16(bb, a, acc): thread holds C[m = m0+rt*16+lr][n = n0+nt*16+lg*4+jj]
// -> 16 x 8B cvt_pk-packed stores/thread (was 64 x 2B scalar in round 13).
// ---------------------------------------------------------------------------
__global__ __launch_bounds__(256) void gemm_qkv(
    const short* __restrict__ XB, const short* __restrict__ qkvT,
    short* __restrict__ Qh, short* __restrict__ Kh, short* __restrict__ Vh)
{
    const int t = threadIdx.x, lane = t & 63, w = t >> 6;
    const int lr = lane & 15, lg = lane >> 4;
    const int m0 = blockIdx.x * 128 + (w >> 1) * 64;
    const int n0 = blockIdx.y * 128 + (w & 1) * 64;

    f32x4 acc[4][4];
    #pragma unroll
    for (int i = 0; i < 4; ++i)
        #pragma unroll
        for (int j = 0; j < 4; ++j) acc[i][j] = z4();

    #pragma unroll
    for (int c = 0; c < 4; ++c) {
        bfrag a[4], bb[4];
        #pragma unroll
        for (int rt = 0; rt < 4; ++rt)
            a[rt] = *(const bfrag*)(XB + (size_t)(m0 + rt * 16 + lr) * 128 + c * 32 + lg * 8);
        #pragma unroll
        for (int nt = 0; nt < 4; ++nt)
            bb[nt] = *(const bfrag*)(qkvT + (size_t)(n0 + nt * 16 + lr) * 128 + c * 32 + lg * 8);
        #pragma unroll
        for (int rt = 0; rt < 4; ++rt)
            #pragma unroll
            for (int nt = 0; nt < 4; ++nt)
                acc[rt][nt] = mfma16(bb[nt], a[rt], acc[rt][nt]);   // SWAPPED
    }

    const int part = blockIdx.y >> 3, c8 = blockIdx.y & 7;
    short* dst = (part == 0) ? Qh : ((part == 1) ? Kh : Vh);
    #pragma unroll
    for (int rt = 0; rt < 4; ++rt) {
        int m = m0 + rt * 16 + lr;
        int b = m >> 11, sl = m & 2047;
        int nh = sl >> 8, s2 = (sl & 255) * 8 + c8;
        size_t rowbase = ((size_t)((b * 8 + nh) * 2048 + s2)) * 128;
        #pragma unroll
        for (int nt = 0; nt < 4; ++nt) {
            int h0 = (w & 1) * 64 + nt * 16 + lg * 4;
            uint2 pk;
            pk.x = cvtpk(acc[rt][nt][0], acc[rt][nt][1]);
            pk.y = cvtpk(acc[rt][nt][2], acc[rt][nt][3]);
            *(uint2*)(dst + rowbase + h0) = pk;
        }
    }
}

// ---------------------------------------------------------------------------
// Transpose V per head: Vh[bn][s2][d] -> Vt[bn][d][s2]. (round-13 verbatim)
// ---------------------------------------------------------------------------
__global__ __launch_bounds__(256) void transp_v(
    const short* __restrict__ Vh, short* __restrict__ Vt)
{
    __shared__ short Ls[64][72];
    const int bn = blockIdx.z, s20 = blockIdx.x * 64, d0 = blockIdx.y * 64;
    const int t = threadIdx.x;
    const short* src = Vh + ((size_t)bn * SEQ + s20) * 128 + d0;
    {
        int r = t >> 2, ch = (t & 3) * 16;
        *(int4*)&Ls[r][ch]     = *(const int4*)(src + (size_t)r * 128 + ch);
        *(int4*)&Ls[r][ch + 8] = *(const int4*)(src + (size_t)r * 128 + ch + 8);
    }
    __syncthreads();
    {
        int dr = t >> 2, ch = (t & 3) * 16;
        short tmp[16];
        #pragma unroll
        for (int i = 0; i < 16; ++i) tmp[i] = Ls[ch + i][dr];
        short* dp = Vt + ((size_t)bn * HDIM + d0 + dr) * SEQ + s20 + ch;
        *(int4*)dp       = *(int4*)&tmp[0];
        *(int4*)(dp + 8) = *(int4*)&tmp[8];
    }
}

// ---------------------------------------------------------------------------
// attn12 = attn10 + two VALU cuts (VALUBusy 51% was the critical pipe):
//  (1) l via P*ones MFMA in C-layout (attn9-validated): -16 add -2 shfl /step
//      on VALU, +2 MFMA on the 17%-busy matrix pipe; epilogue shuffles gone;
//      rescale folds into the existing alj loop.
//  (2) max3-shaped row-max tree (T17): nested triples -> v_max3_f32, 15->8.
// Everything else byte-identical to attn10 (83.4 us best).
// ---------------------------------------------------------------------------
__global__ __launch_bounds__(256) void attn12(
    const short* __restrict__ Qh, const short* __restrict__ Kh,
    const short* __restrict__ Vt, short* __restrict__ Y)
{
    __shared__ __align__(16) short Kls[2][64 * 128];   // 32 KB
    __shared__ __align__(16) short Vls[2][128 * 64];   // 32 KB

    const int t = threadIdx.x, lane = t & 63, w = t >> 6;
    const int lr = lane & 15, lg = lane >> 4;

    const int g  = blockIdx.x;        // 0..511
    const int bn = g & 31;            // head id; bn%8 == g%8 (XCD affinity)
    const int pp = g >> 5;            // pair id 0..15 -> tiles (pp, 31-pp)
    const int b  = bn >> 3, n = bn & 7;

    const short* Qb = Qh + (size_t)bn * SEQ * HDIM;
    const short* Kb = Kh + (size_t)bn * SEQ * HDIM;
    const short* Vb = Vt + (size_t)bn * HDIM * SEQ;

    auto stageK = [&](int buf, int k0) {
        #pragma unroll
        for (int i = 0; i < 4; ++i) {
            const int q = w * 4 + i;
            const int rowK = q * 4 + (lane >> 4);
            const short* src = Kb + (size_t)(k0 + rowK) * 128 + (((lane & 15) ^ (rowK & 7)) * 8);
            __builtin_amdgcn_global_load_lds(
                (const __attribute__((address_space(1))) unsigned int*)src,
                (__attribute__((address_space(3))) unsigned int*)&Kls[buf][q * 512 + lane * 8],
                16, 0, 0);
        }
    };
    auto stageV = [&](int buf, int k0) {
        #pragma unroll
        for (int i = 0; i < 4; ++i) {
            const int q = w * 4 + i;
            const int d = q * 8 + (lane >> 3);
            const short* src = Vb + (size_t)d * SEQ + k0 + (((lane & 7) ^ (d & 7)) * 8);
            __builtin_amdgcn_global_load_lds(
                (const __attribute__((address_space(1))) unsigned int*)src,
                (__attribute__((address_space(3))) unsigned int*)&Vls[buf][q * 512 + lane * 8],
                16, 0, 0);
        }
    };

    const int sw = lr & 7;
    const bool hi16 = (lg & 1);

    bfrag ones;
    #pragma unroll
    for (int k = 0; k < 8; ++k) ones[k] = (short)0x3F80;   // bf16 1.0

    #pragma unroll 1
    for (int phase = 0; phase < 2; ++phase) {
        const int tile = phase ? pp : (31 - pp);    // long tile first
        const int q0 = tile * 64 + w * 16;

        bfrag qf[4];
        #pragma unroll
        for (int c = 0; c < 4; ++c)
            qf[c] = *(const bfrag*)(Qb + (size_t)(q0 + lr) * 128 + c * 32 + lg * 8);

        float mcs = -1.0e30f;         // per-lane: q = q0 + lr
        f32x4 l4 = z4();              // C-layout row-sums: l4[j] for q0+lg*4+j
        f32x4 o[8];
        #pragma unroll
        for (int dt = 0; dt < 8; ++dt) o[dt] = z4();

        stageV(0, 0);
        stageK(0, 0);
        __syncthreads();   // buffer 0 staged

        for (int s = 0; s <= tile; ++s) {
            const int cur = s & 1;
            const int k0 = s * 64;
            if (s < tile) { stageV(cur ^ 1, k0 + 64); stageK(cur ^ 1, k0 + 64); }

            f32x4 sA[4];
            #pragma unroll
            for (int kt = 0; kt < 4; ++kt) sA[kt] = z4();
            const int ktend = (s == tile) ? (w + 1) : 4;
            __builtin_amdgcn_s_setprio(1);
            #pragma unroll
            for (int kt = 0; kt < 4; ++kt) {
                if (kt < ktend) {   // wave-uniform
                    const char* kbase = (const char*)&Kls[cur][0] + (kt * 16 + lr) * 256;
                    #pragma unroll
                    for (int c = 0; c < 4; ++c) {
                        bfrag kb = *(const bfrag*)(kbase + (((c * 4 + lg) ^ sw) * 16));
                        sA[kt] = mfma16(kb, qf[c], sA[kt]);   // swapped operands
                    }
                }
            }
            __builtin_amdgcn_s_setprio(0);

            if (s == tile) {
                #pragma unroll
                for (int kt = 0; kt < 4; ++kt)
                    #pragma unroll
                    for (int j = 0; j < 4; ++j)
                        if (kt * 16 + lg * 4 + j > w * 16 + lr)
                            sA[kt][j] = -3.0e38f;
            }

            // ---- row max: max3-shaped tree (8 ops) + 2 cross-lg shuffles
            float mx = fmaxf(fmaxf(sA[0][0], sA[0][1]), sA[0][2]);
            mx = fmaxf(fmaxf(mx, sA[0][3]), sA[1][0]);
            mx = fmaxf(fmaxf(mx, sA[1][1]), sA[1][2]);
            mx = fmaxf(fmaxf(mx, sA[1][3]), sA[2][0]);
            mx = fmaxf(fmaxf(mx, sA[2][1]), sA[2][2]);
            mx = fmaxf(fmaxf(mx, sA[2][3]), sA[3][0]);
            mx = fmaxf(fmaxf(mx, sA[3][1]), sA[3][2]);
            mx = fmaxf(mx, sA[3][3]);
            mx = fmaxf(mx, __shfl_xor(mx, 16));
            mx = fmaxf(mx, __shfl_xor(mx, 32));
            const float pmx = mx * CS;

            // ---- T13 defer-rescale (rare)
            if (__any((pmx > mcs + 8.0f) ? 1 : 0)) {
                float nm = fmaxf(mcs, pmx);
                float al = exp2f(mcs - nm);
                mcs = nm;
                float alj[4];
                #pragma unroll
                for (int j = 0; j < 4; ++j) alj[j] = __shfl(al, lg * 4 + j);
                #pragma unroll
                for (int j = 0; j < 4; ++j) l4[j] *= alj[j];
                #pragma unroll
                for (int dt = 0; dt < 8; ++dt)
                    #pragma unroll
                    for (int j = 0; j < 4; ++j) o[dt][j] *= alj[j];
            }

            // ---- P = exp2(S*CS - mcs) (lane-local row); no VALU l-sum
            float p[4][4];
            #pragma unroll
            for (int kt = 0; kt < 4; ++kt)
                #pragma unroll
                for (int j = 0; j < 4; ++j)
                    p[kt][j] = exp2f(sA[kt][j] * CS - mcs);

            bfrag pa0, pa1;
            redist(p, hi16, pa0, pa1);

            // ---- l via P*ones MFMA (C-layout, matrix pipe)
            l4 = mfma16(pa0, ones, mfma16(pa1, ones, l4));

            __builtin_amdgcn_s_setprio(1);
            #pragma unroll
            for (int dt = 0; dt < 8; ++dt) {
                const char* vbase = (const char*)&Vls[cur][0] + (dt * 16 + lr) * 128;
                bfrag vb0 = *(const bfrag*)(vbase + ((lg ^ sw) * 16));
                bfrag vb1 = *(const bfrag*)(vbase + (((4 + lg) ^ sw) * 16));
                o[dt] = mfma16(pa0, vb0, o[dt]);
                o[dt] = mfma16(pa1, vb1, o[dt]);
            }
            __builtin_amdgcn_s_setprio(0);

            __syncthreads();
        }

        // ---- epilogue: inv directly from C-layout l4 (no shuffles)
        float inv[4];
        #pragma unroll
        for (int j = 0; j < 4; ++j) inv[j] = 1.0f / l4[j];
        #pragma unroll
        for (int j = 0; j < 4; ++j) {
            int s2 = q0 + lg * 4 + j;
            size_t yrow = (size_t)b * SEQ + n * 256 + (s2 >> 3);
            short* yp = Y + yrow * YN + (s2 & 7) * 128 + lr;
            #pragma unroll
            for (int dt = 0; dt < 8; ++dt)
                yp[dt * 16] = f2bf(o[dt][j] * inv[j]);
        }
    }
}

// ---------------------------------------------------------------------------
// GEMM2 (SWAPPED-operand): out[8192][128] (f32) = Yb @ proj, B as projT.
// Thread holds out[m = m0+lr][n = n0+nt*16+lg*4+jj] -> 4 float4 stores.
// ---------------------------------------------------------------------------
__global__ __launch_bounds__(128) void gemm_out(
    const short* __restrict__ Yb, const short* __restrict__ projT, float* __restrict__ out)
{
    const int t = threadIdx.x, lane = t & 63, w = t >> 6;   // w in 0..1
    const int lr = lane & 15, lg = lane >> 4;
    const int m0 = blockIdx.x * 16;
    const int n0 = w * 64;

    f32x4 acc[4];
    #pragma unroll
    for (int j = 0; j < 4; ++j) acc[j] = z4();

    for (int c = 0; c < 32; ++c) {
        bfrag a = *(const bfrag*)(Yb + (size_t)(m0 + lr) * YN + c * 32 + lg * 8);
        #pragma unroll
        for (int nt = 0; nt < 4; ++nt) {
            bfrag bb = *(const bfrag*)(projT + (size_t)(n0 + nt * 16 + lr) * YN + c * 32 + lg * 8);
            acc[nt] = mfma16(bb, a, acc[nt]);   // SWAPPED
        }
    }
    #pragma unroll
    for (int nt = 0; nt < 4; ++nt)
        *(f32x4*)(out + (size_t)(m0 + lr) * HDIM + n0 + nt * 16 + lg * 4) = acc[nt];
}

// ---------------------------------------------------------------------------
extern "C" void kernel_launch(void* const* d_in, const int* in_sizes, int n_in,
                              void* d_out, int out_size, void* d_ws, size_t ws_size,
                              hipStream_t stream)
{
    const float* x    = (const float*)d_in[0];  // [4,2048,128]
    const float* qkv  = (const float*)d_in[1];  // [128,3072]
    const float* proj = (const float*)d_in[2];  // [1024,128]
    float* out = (float*)d_out;                 // [8192,128]

    const size_t HEADSZ = (size_t)32 * SEQ * HDIM;        // 8,388,608 elements

    short* XB    = (short*)d_ws;                          // 2 MB
    short* qkvT  = XB    + (size_t)MROWS * HDIM;          // 0.75 MB
    short* projT = qkvT  + (size_t)QKVN * HDIM;           // 0.25 MB
    short* Qh    = projT + (size_t)HDIM * YN;             // 16 MB
    short* Kh    = Qh    + HEADSZ;                        // 16 MB
    short* Vh    = Kh    + HEADSZ;                        // 16 MB (row-major)
    short* Vtb   = Vh    + HEADSZ;                        // 16 MB (transposed)
    short* Yb    = Vtb   + HEADSZ;                        // 16 MB  (~83 MB total)

    conv_x    <<<MROWS * HDIM / 1024, 256, 0, stream>>>(x, XB);
    conv_qkvT <<<QKVN * HDIM / 256,  256, 0, stream>>>(qkv, qkvT);
    conv_projT<<<HDIM * YN / 256,    256, 0, stream>>>(proj, projT);

    gemm_qkv<<<dim3(MROWS / 128, QKVN / 128), 256, 0, stream>>>(XB, qkvT, Qh, Kh, Vh);
    transp_v<<<dim3(SEQ / 64, HDIM / 64, 32), 256, 0, stream>>>(Vh, Vtb);
    attn12  <<<512, 256, 0, stream>>>(Qh, Kh, Vtb, Yb);
    gemm_out<<<MROWS / 16, 128, 0, stream>>>(Yb, projT, out);
}

// Round 19
// 143.363 us; speedup vs baseline: 1.3161x; 1.0391x over previous
//
#include <hip/hip_runtime.h>
#include <math.h>

// Problem constants
#define BATCH 4
#define SEQ   2048
#define HDIM  128
#define NHEAD 8
#define MROWS (BATCH*SEQ)    // 8192
#define QKVN  (3*NHEAD*HDIM) // 3072
#define YN    (NHEAD*HDIM)   // 1024

#define CS 0.12751744f   // (1/sqrt(128)) * log2(e)

using bfrag = __attribute__((ext_vector_type(8))) short;  // 8 bf16 (4 VGPRs)
using f32x4 = __attribute__((ext_vector_type(4))) float;
using s16x4 = __attribute__((ext_vector_type(4))) short;

__device__ __forceinline__ f32x4 mfma16(bfrag a, bfrag b, f32x4 c) {
    return __builtin_amdgcn_mfma_f32_16x16x32_bf16(a, b, c, 0, 0, 0);
}
__device__ __forceinline__ short f2bf(float f) {
    union { float f; unsigned u; } v; v.f = f;
    unsigned r = v.u + 0x7FFFu + ((v.u >> 16) & 1u);  // RNE
    return (short)(r >> 16);
}
__device__ __forceinline__ unsigned cvtpk(float lo, float hi) {
    unsigned r;
    asm("v_cvt_pk_bf16_f32 %0, %1, %2" : "=v"(r) : "v"(lo), "v"(hi));
    return r;   // bits[15:0]=bf16(lo), bits[31:16]=bf16(hi)
}
__device__ __forceinline__ void perm32swap(unsigned &x, unsigned &y) {
    asm volatile("v_permlane32_swap_b32 %0, %1" : "+v"(x), "+v"(y));
}
__device__ __forceinline__ f32x4 z4() { f32x4 z; z[0]=0.f; z[1]=0.f; z[2]=0.f; z[3]=0.f; return z; }

// In-register P redistribution (C-layout -> A-frag layout), validated attn8/10/12.
__device__ __forceinline__ void redist(const float p[4][4], bool hi16,
                                       bfrag &pa0o, bfrag &pa1o) {
    unsigned pk0[2], pk1[2], pk2[2], pk3[2];
    pk0[0] = cvtpk(p[0][0], p[0][1]); pk0[1] = cvtpk(p[0][2], p[0][3]);
    pk1[0] = cvtpk(p[1][0], p[1][1]); pk1[1] = cvtpk(p[1][2], p[1][3]);
    pk2[0] = cvtpk(p[2][0], p[2][1]); pk2[1] = cvtpk(p[2][2], p[2][3]);
    pk3[0] = cvtpk(p[3][0], p[3][1]); pk3[1] = cvtpk(p[3][2], p[3][3]);
    uint4 w0, w1;
    {
        unsigned A = pk0[0], C = pk1[0];
        perm32swap(A, C);
        unsigned A16 = __shfl_xor((int)A, 16), C16 = __shfl_xor((int)C, 16);
        w0.x = hi16 ? C16 : A;
        w0.z = hi16 ? C   : A16;
        unsigned B = pk0[1], D = pk1[1];
        perm32swap(B, D);
        unsigned B16 = __shfl_xor((int)B, 16), D16 = __shfl_xor((int)D, 16);
        w0.y = hi16 ? D16 : B;
        w0.w = hi16 ? D   : B16;
    }
    {
        unsigned E = pk2[0], G = pk3[0];
        perm32swap(E, G);
        unsigned E16 = __shfl_xor((int)E, 16), G16 = __shfl_xor((int)G, 16);
        w1.x = hi16 ? G16 : E;
        w1.z = hi16 ? G   : E16;
        unsigned F = pk2[1], H = pk3[1];
        perm32swap(F, H);
        unsigned F16 = __shfl_xor((int)F, 16), H16 = __shfl_xor((int)H, 16);
        w1.y = hi16 ? H16 : F;
        w1.w = hi16 ? H   : H16 * 0 + F16;   // placeholder avoided below
    }
    // NOTE: w1.w must be (hi16 ? H : F16) — write it explicitly to avoid typos.
    {
        unsigned F = pk2[1], H = pk3[1];
        // recompute cleanly (compiler CSEs; keeps the validated mapping exact)
        perm32swap(F, H);
        unsigned F16 = __shfl_xor((int)F, 16), H16 = __shfl_xor((int)H, 16);
        w1.y = hi16 ? H16 : F;
        w1.w = hi16 ? H   : F16;
    }
    union { uint4 u; bfrag f; } cv0, cv1;
    cv0.u = w0; cv1.u = w1;
    pa0o = cv0.f; pa1o = cv1.f;
}

// ---------------------------------------------------------------------------
// Merged converters (one launch, r18's conv_all — trivially deterministic):
// blocks [0,1024) conv_x, [1024,2560) qkvT, [2560,3072) projT.
// ---------------------------------------------------------------------------
__global__ __launch_bounds__(256) void conv_all(
    const float* __restrict__ x, const float* __restrict__ qkv,
    const float* __restrict__ proj, short* __restrict__ XB,
    short* __restrict__ qT, short* __restrict__ pT)
{
    const int bid = blockIdx.x;
    if (bid < 1024) {
        int i = (bid * 256 + threadIdx.x) * 4;
        float4 v = *(const float4*)(x + i);
        s16x4 o; o[0] = f2bf(v.x); o[1] = f2bf(v.y); o[2] = f2bf(v.z); o[3] = f2bf(v.w);
        *(s16x4*)(XB + i) = o;
    } else if (bid < 2560) {
        int t = (bid - 1024) * 256 + threadIdx.x;   // 3072*128
        int n = t >> 7, k = t & 127;
        qT[t] = f2bf(qkv[(size_t)k * QKVN + n]);
    } else {
        int t = (bid - 2560) * 256 + threadIdx.x;   // 128*1024
        int h = t >> 10, r = t & 1023;
        pT[t] = f2bf(proj[(size_t)r * HDIM + h]);
    }
}

// ---------------------------------------------------------------------------
// GEMM1 (r17 verbatim): XB(bf16) @ qkv -> per-head Qh/Kh/Vh, swapped-operand
// packed stores (16 x 8B cvt_pk stores/thread).
// ---------------------------------------------------------------------------
__global__ __launch_bounds__(256) void gemm_qkv(
    const short* __restrict__ XB, const short* __restrict__ qkvT,
    short* __restrict__ Qh, short* __restrict__ Kh, short* __restrict__ Vh)
{
    const int t = threadIdx.x, lane = t & 63, w = t >> 6;
    const int lr = lane & 15, lg = lane >> 4;
    const int m0 = blockIdx.x * 128 + (w >> 1) * 64;
    const int n0 = blockIdx.y * 128 + (w & 1) * 64;

    f32x4 acc[4][4];
    #pragma unroll
    for (int i = 0; i < 4; ++i)
        #pragma unroll
        for (int j = 0; j < 4; ++j) acc[i][j] = z4();

    #pragma unroll
    for (int c = 0; c < 4; ++c) {
        bfrag a[4], bb[4];
        #pragma unroll
        for (int rt = 0; rt < 4; ++rt)
            a[rt] = *(const bfrag*)(XB + (size_t)(m0 + rt * 16 + lr) * 128 + c * 32 + lg * 8);
        #pragma unroll
        for (int nt = 0; nt < 4; ++nt)
            bb[nt] = *(const bfrag*)(qkvT + (size_t)(n0 + nt * 16 + lr) * 128 + c * 32 + lg * 8);
        #pragma unroll
        for (int rt = 0; rt < 4; ++rt)
            #pragma unroll
            for (int nt = 0; nt < 4; ++nt)
                acc[rt][nt] = mfma16(bb[nt], a[rt], acc[rt][nt]);   // SWAPPED
    }

    const int part = blockIdx.y >> 3, c8 = blockIdx.y & 7;
    short* dst = (part == 0) ? Qh : ((part == 1) ? Kh : Vh);
    #pragma unroll
    for (int rt = 0; rt < 4; ++rt) {
        int m = m0 + rt * 16 + lr;
        int b = m >> 11, sl = m & 2047;
        int nh = sl >> 8, s2 = (sl & 255) * 8 + c8;
        size_t rowbase = ((size_t)((b * 8 + nh) * 2048 + s2)) * 128;
        #pragma unroll
        for (int nt = 0; nt < 4; ++nt) {
            int h0 = (w & 1) * 64 + nt * 16 + lg * 4;
            uint2 pk;
            pk.x = cvtpk(acc[rt][nt][0], acc[rt][nt][1]);
            pk.y = cvtpk(acc[rt][nt][2], acc[rt][nt][3]);
            *(uint2*)(dst + rowbase + h0) = pk;
        }
    }
}

// ---------------------------------------------------------------------------
// Transpose V per head: Vh[bn][s2][d] -> Vt[bn][d][s2]. (r13 verbatim)
// ---------------------------------------------------------------------------
__global__ __launch_bounds__(256) void transp_v(
    const short* __restrict__ Vh, short* __restrict__ Vt)
{
    __shared__ short Ls[64][72];
    const int bn = blockIdx.z, s20 = blockIdx.x * 64, d0 = blockIdx.y * 64;
    const int t = threadIdx.x;
    const short* src = Vh + ((size_t)bn * SEQ + s20) * 128 + d0;
    {
        int r = t >> 2, ch = (t & 3) * 16;
        *(int4*)&Ls[r][ch]     = *(const int4*)(src + (size_t)r * 128 + ch);
        *(int4*)&Ls[r][ch + 8] = *(const int4*)(src + (size_t)r * 128 + ch + 8);
    }
    __syncthreads();
    {
        int dr = t >> 2, ch = (t & 3) * 16;
        short tmp[16];
        #pragma unroll
        for (int i = 0; i < 16; ++i) tmp[i] = Ls[ch + i][dr];
        short* dp = Vt + ((size_t)bn * HDIM + d0 + dr) * SEQ + s20 + ch;
        *(int4*)dp       = *(int4*)&tmp[0];
        *(int4*)(dp + 8) = *(int4*)&tmp[8];
    }
}

// ---------------------------------------------------------------------------
// attn12 (r17 verbatim — 81.4 us proven): 16 q-rows/wave, QBLK=64,
// tile-pairing (pp, 31-pp) -> 33 uniform steps, XCD affinity, K+V dbuf
// global_load_lds staging, one barrier/step, static kt + wave-uniform
// predicate, swapped QK^T in-register softmax, in-reg P redistribution,
// l via P*ones MFMA (C-layout), max3-shaped row-max, T13 defer-rescale.
// ---------------------------------------------------------------------------
__global__ __launch_bounds__(256) void attn12(
    const short* __restrict__ Qh, const short* __restrict__ Kh,
    const short* __restrict__ Vt, short* __restrict__ Y)
{
    __shared__ __align__(16) short Kls[2][64 * 128];   // 32 KB
    __shared__ __align__(16) short Vls[2][128 * 64];   // 32 KB

    const int t = threadIdx.x, lane = t & 63, w = t >> 6;
    const int lr = lane & 15, lg = lane >> 4;

    const int g  = blockIdx.x;        // 0..511
    const int bn = g & 31;            // head id; bn%8 == g%8 (XCD affinity)
    const int pp = g >> 5;            // pair id 0..15 -> tiles (pp, 31-pp)
    const int b  = bn >> 3, n = bn & 7;

    const short* Qb = Qh + (size_t)bn * SEQ * HDIM;
    const short* Kb = Kh + (size_t)bn * SEQ * HDIM;
    const short* Vb = Vt + (size_t)bn * HDIM * SEQ;

    auto stageK = [&](int buf, int k0) {
        #pragma unroll
        for (int i = 0; i < 4; ++i) {
            const int q = w * 4 + i;
            const int rowK = q * 4 + (lane >> 4);
            const short* src = Kb + (size_t)(k0 + rowK) * 128 + (((lane & 15) ^ (rowK & 7)) * 8);
            __builtin_amdgcn_global_load_lds(
                (const __attribute__((address_space(1))) unsigned int*)src,
                (__attribute__((address_space(3))) unsigned int*)&Kls[buf][q * 512 + lane * 8],
                16, 0, 0);
        }
    };
    auto stageV = [&](int buf, int k0) {
        #pragma unroll
        for (int i = 0; i < 4; ++i) {
            const int q = w * 4 + i;
            const int d = q * 8 + (lane >> 3);
            const short* src = Vb + (size_t)d * SEQ + k0 + (((lane & 7) ^ (d & 7)) * 8);
            __builtin_amdgcn_global_load_lds(
                (const __attribute__((address_space(1))) unsigned int*)src,
                (__attribute__((address_space(3))) unsigned int*)&Vls[buf][q * 512 + lane * 8],
                16, 0, 0);
        }
    };

    const int sw = lr & 7;
    const bool hi16 = (lg & 1);

    bfrag ones;
    #pragma unroll
    for (int k = 0; k < 8; ++k) ones[k] = (short)0x3F80;   // bf16 1.0

    #pragma unroll 1
    for (int phase = 0; phase < 2; ++phase) {
        const int tile = phase ? pp : (31 - pp);    // long tile first
        const int q0 = tile * 64 + w * 16;

        bfrag qf[4];
        #pragma unroll
        for (int c = 0; c < 4; ++c)
            qf[c] = *(const bfrag*)(Qb + (size_t)(q0 + lr) * 128 + c * 32 + lg * 8);

        float mcs = -1.0e30f;         // per-lane: q = q0 + lr
        f32x4 l4 = z4();              // C-layout row-sums
        f32x4 o[8];
        #pragma unroll
        for (int dt = 0; dt < 8; ++dt) o[dt] = z4();

        stageV(0, 0);
        stageK(0, 0);
        __syncthreads();   // buffer 0 staged

        for (int s = 0; s <= tile; ++s) {
            const int cur = s & 1;
            const int k0 = s * 64;
            if (s < tile) { stageV(cur ^ 1, k0 + 64); stageK(cur ^ 1, k0 + 64); }

            f32x4 sA[4];
            #pragma unroll
            for (int kt = 0; kt < 4; ++kt) sA[kt] = z4();
            const int ktend = (s == tile) ? (w + 1) : 4;
            __builtin_amdgcn_s_setprio(1);
            #pragma unroll
            for (int kt = 0; kt < 4; ++kt) {
                if (kt < ktend) {   // wave-uniform
                    const char* kbase = (const char*)&Kls[cur][0] + (kt * 16 + lr) * 256;
                    #pragma unroll
                    for (int c = 0; c < 4; ++c) {
                        bfrag kb = *(const bfrag*)(kbase + (((c * 4 + lg) ^ sw) * 16));
                        sA[kt] = mfma16(kb, qf[c], sA[kt]);   // swapped operands
                    }
                }
            }
            __builtin_amdgcn_s_setprio(0);

            if (s == tile) {
                #pragma unroll
                for (int kt = 0; kt < 4; ++kt)
                    #pragma unroll
                    for (int j = 0; j < 4; ++j)
                        if (kt * 16 + lg * 4 + j > w * 16 + lr)
                            sA[kt][j] = -3.0e38f;
            }

            // ---- row max: max3-shaped tree + 2 cross-lg shuffles
            float mx = fmaxf(fmaxf(sA[0][0], sA[0][1]), sA[0][2]);
            mx = fmaxf(fmaxf(mx, sA[0][3]), sA[1][0]);
            mx = fmaxf(fmaxf(mx, sA[1][1]), sA[1][2]);
            mx = fmaxf(fmaxf(mx, sA[1][3]), sA[2][0]);
            mx = fmaxf(fmaxf(mx, sA[2][1]), sA[2][2]);
            mx = fmaxf(fmaxf(mx, sA[2][3]), sA[3][0]);
            mx = fmaxf(fmaxf(mx, sA[3][1]), sA[3][2]);
            mx = fmaxf(mx, sA[3][3]);
            mx = fmaxf(mx, __shfl_xor(mx, 16));
            mx = fmaxf(mx, __shfl_xor(mx, 32));
            const float pmx = mx * CS;

            // ---- T13 defer-rescale (rare)
            if (__any((pmx > mcs + 8.0f) ? 1 : 0)) {
                float nm = fmaxf(mcs, pmx);
                float al = exp2f(mcs - nm);
                mcs = nm;
                float alj[4];
                #pragma unroll
                for (int j = 0; j < 4; ++j) alj[j] = __shfl(al, lg * 4 + j);
                #pragma unroll
                for (int j = 0; j < 4; ++j) l4[j] *= alj[j];
                #pragma unroll
                for (int dt = 0; dt < 8; ++dt)
                    #pragma unroll
                    for (int j = 0; j < 4; ++j) o[dt][j] *= alj[j];
            }

            // ---- P = exp2(S*CS - mcs) (lane-local row)
            float p[4][4];
            #pragma unroll
            for (int kt = 0; kt < 4; ++kt)
                #pragma unroll
                for (int j = 0; j < 4; ++j)
                    p[kt][j] = exp2f(sA[kt][j] * CS - mcs);

            bfrag pa0, pa1;
            redist(p, hi16, pa0, pa1);

            // ---- l via P*ones MFMA (C-layout, matrix pipe)
            l4 = mfma16(pa0, ones, mfma16(pa1, ones, l4));

            __builtin_amdgcn_s_setprio(1);
            #pragma unroll
            for (int dt = 0; dt < 8; ++dt) {
                const char* vbase = (const char*)&Vls[cur][0] + (dt * 16 + lr) * 128;
                bfrag vb0 = *(const bfrag*)(vbase + ((lg ^ sw) * 16));
                bfrag vb1 = *(const bfrag*)(vbase + (((4 + lg) ^ sw) * 16));
                o[dt] = mfma16(pa0, vb0, o[dt]);
                o[dt] = mfma16(pa1, vb1, o[dt]);
            }
            __builtin_amdgcn_s_setprio(0);

            __syncthreads();
        }

        // ---- epilogue: inv directly from C-layout l4 (no shuffles)
        float inv[4];
        #pragma unroll
        for (int j = 0; j < 4; ++j) inv[j] = 1.0f / l4[j];
        #pragma unroll
        for (int j = 0; j < 4; ++j) {
            int s2 = q0 + lg * 4 + j;
            size_t yrow = (size_t)b * SEQ + n * 256 + (s2 >> 3);
            short* yp = Y + yrow * YN + (s2 & 7) * 128 + lr;
            #pragma unroll
            for (int dt = 0; dt < 8; ++dt)
                yp[dt * 16] = f2bf(o[dt][j] * inv[j]);
        }
    }
}

// ---------------------------------------------------------------------------
// GEMM2 (r17 verbatim, swapped-operand float4 stores)
// ---------------------------------------------------------------------------
__global__ __launch_bounds__(128) void gemm_out(
    const short* __restrict__ Yb, const short* __restrict__ projT, float* __restrict__ out)
{
    const int t = threadIdx.x, lane = t & 63, w = t >> 6;   // w in 0..1
    const int lr = lane & 15, lg = lane >> 4;
    const int m0 = blockIdx.x * 16;
    const int n0 = w * 64;

    f32x4 acc[4];
    #pragma unroll
    for (int j = 0; j < 4; ++j) acc[j] = z4();

    for (int c = 0; c < 32; ++c) {
        bfrag a = *(const bfrag*)(Yb + (size_t)(m0 + lr) * YN + c * 32 + lg * 8);
        #pragma unroll
        for (int nt = 0; nt < 4; ++nt) {
            bfrag bb = *(const bfrag*)(projT + (size_t)(n0 + nt * 16 + lr) * YN + c * 32 + lg * 8);
            acc[nt] = mfma16(bb, a, acc[nt]);   // SWAPPED
        }
    }
    #pragma unroll
    for (int nt = 0; nt < 4; ++nt)
        *(f32x4*)(out + (size_t)(m0 + lr) * HDIM + n0 + nt * 16 + lg * 4) = acc[nt];
}

// ---------------------------------------------------------------------------
extern "C" void kernel_launch(void* const* d_in, const int* in_sizes, int n_in,
                              void* d_out, int out_size, void* d_ws, size_t ws_size,
                              hipStream_t stream)
{
    const float* x    = (const float*)d_in[0];  // [4,2048,128]
    const float* qkv  = (const float*)d_in[1];  // [128,3072]
    const float* proj = (const float*)d_in[2];  // [1024,128]
    float* out = (float*)d_out;                 // [8192,128]

    const size_t HEADSZ = (size_t)32 * SEQ * HDIM;        // 8,388,608 elements

    short* XB    = (short*)d_ws;                          // 2 MB
    short* qkvT  = XB    + (size_t)MROWS * HDIM;          // 0.75 MB
    short* projT = qkvT  + (size_t)QKVN * HDIM;           // 0.25 MB
    short* Qh    = projT + (size_t)HDIM * YN;             // 16 MB
    short* Kh    = Qh    + HEADSZ;                        // 16 MB
    short* Vh    = Kh    + HEADSZ;                        // 16 MB (row-major)
    short* Vtb   = Vh    + HEADSZ;                        // 16 MB (transposed)
    short* Yb    = Vtb   + HEADSZ;                        // 16 MB  (~83 MB total)

    conv_all<<<3072, 256, 0, stream>>>(x, qkv, proj, XB, qkvT, projT);
    gemm_qkv<<<dim3(MROWS / 128, QKVN / 128), 256, 0, stream>>>(XB, qkvT, Qh, Kh, Vh);
    transp_v<<<dim3(SEQ / 64, HDIM / 64, 32), 256, 0, stream>>>(Vh, Vtb);
    attn12  <<<512, 256, 0, stream>>>(Qh, Kh, Vtb, Yb);
    gemm_out<<<MROWS / 16, 128, 0, stream>>>(Yb, projT, out);
}

// Round 20
// 142.225 us; speedup vs baseline: 1.3266x; 1.0080x over previous
//
#include <hip/hip_runtime.h>
#include <math.h>

// Problem constants
#define BATCH 4
#define SEQ   2048
#define HDIM  128
#define NHEAD 8
#define MROWS (BATCH*SEQ)    // 8192
#define QKVN  (3*NHEAD*HDIM) // 3072
#define YN    (NHEAD*HDIM)   // 1024

#define CS 0.12751744f   // (1/sqrt(128)) * log2(e)

using bfrag = __attribute__((ext_vector_type(8))) short;  // 8 bf16 (4 VGPRs)
using f32x4 = __attribute__((ext_vector_type(4))) float;
using s16x4 = __attribute__((ext_vector_type(4))) short;

__device__ __forceinline__ f32x4 mfma16(bfrag a, bfrag b, f32x4 c) {
    return __builtin_amdgcn_mfma_f32_16x16x32_bf16(a, b, c, 0, 0, 0);
}
__device__ __forceinline__ short f2bf(float f) {
    union { float f; unsigned u; } v; v.f = f;
    unsigned r = v.u + 0x7FFFu + ((v.u >> 16) & 1u);  // RNE
    return (short)(r >> 16);
}
__device__ __forceinline__ unsigned cvtpk(float lo, float hi) {
    unsigned r;
    asm("v_cvt_pk_bf16_f32 %0, %1, %2" : "=v"(r) : "v"(lo), "v"(hi));
    return r;   // bits[15:0]=bf16(lo), bits[31:16]=bf16(hi)
}
__device__ __forceinline__ void perm32swap(unsigned &x, unsigned &y) {
    asm volatile("v_permlane32_swap_b32 %0, %1" : "+v"(x), "+v"(y));
}
__device__ __forceinline__ f32x4 z4() { f32x4 z; z[0]=0.f; z[1]=0.f; z[2]=0.f; z[3]=0.f; return z; }

// In-register P redistribution (C-layout -> A-frag layout), validated attn8/10/12.
__device__ __forceinline__ void redist(const float p[4][4], bool hi16,
                                       bfrag &pa0o, bfrag &pa1o) {
    unsigned pk0[2], pk1[2], pk2[2], pk3[2];
    pk0[0] = cvtpk(p[0][0], p[0][1]); pk0[1] = cvtpk(p[0][2], p[0][3]);
    pk1[0] = cvtpk(p[1][0], p[1][1]); pk1[1] = cvtpk(p[1][2], p[1][3]);
    pk2[0] = cvtpk(p[2][0], p[2][1]); pk2[1] = cvtpk(p[2][2], p[2][3]);
    pk3[0] = cvtpk(p[3][0], p[3][1]); pk3[1] = cvtpk(p[3][2], p[3][3]);
    uint4 w0, w1;
    {
        unsigned A = pk0[0], C = pk1[0];
        perm32swap(A, C);
        unsigned A16 = __shfl_xor((int)A, 16), C16 = __shfl_xor((int)C, 16);
        w0.x = hi16 ? C16 : A;
        w0.z = hi16 ? C   : A16;
        unsigned B = pk0[1], D = pk1[1];
        perm32swap(B, D);
        unsigned B16 = __shfl_xor((int)B, 16), D16 = __shfl_xor((int)D, 16);
        w0.y = hi16 ? D16 : B;
        w0.w = hi16 ? D   : B16;
    }
    {
        unsigned E = pk2[0], G = pk3[0];
        perm32swap(E, G);
        unsigned E16 = __shfl_xor((int)E, 16), G16 = __shfl_xor((int)G, 16);
        w1.x = hi16 ? G16 : E;
        w1.z = hi16 ? G   : E16;
        unsigned F = pk2[1], H = pk3[1];
        perm32swap(F, H);
        unsigned F16 = __shfl_xor((int)F, 16), H16 = __shfl_xor((int)H, 16);
        w1.y = hi16 ? H16 : F;
        w1.w = hi16 ? H   : F16;
    }
    union { uint4 u; bfrag f; } cv0, cv1;
    cv0.u = w0; cv1.u = w1;
    pa0o = cv0.f; pa1o = cv1.f;
}

// ---------------------------------------------------------------------------
// Merged converters, all COALESCED (one launch):
//  blocks [0,1024):     x f32 -> XB bf16 (straight convert)
//  blocks [1024,1120):  qkv [128][3072] f32 -> qkvT [3072][128] bf16
//                       LDS-tiled 64x64 transpose-convert (coalesced both sides)
//  blocks [1120,1152):  proj [1024][128] f32 -> projT [128][1024] bf16 (same)
// (r19's scalar transposes read with 12KB-stride per lane: ~16x over-fetch.)
// ---------------------------------------------------------------------------
__global__ __launch_bounds__(256) void conv_all(
    const float* __restrict__ x, const float* __restrict__ qkv,
    const float* __restrict__ proj, short* __restrict__ XB,
    short* __restrict__ qT, short* __restrict__ pT)
{
    __shared__ short Ls[64][72];
    const int bid = blockIdx.x, t = threadIdx.x;
    if (bid < 1024) {
        int i = (bid * 256 + t) * 4;
        float4 v = *(const float4*)(x + i);
        s16x4 o; o[0] = f2bf(v.x); o[1] = f2bf(v.y); o[2] = f2bf(v.z); o[3] = f2bf(v.w);
        *(s16x4*)(XB + i) = o;
        return;
    }
    // tiled transpose-convert: src [SR][SC] f32 -> dst [SC][SR] bf16
    const float* src;
    short* dst;
    int r0, c0, sc, sr;   // tile origin (row,col in src), src cols, src rows(=dst cols)
    if (bid < 1120) {
        int b2 = bid - 1024;                 // 96 blocks: 2 k-tiles x 48 n-tiles
        r0 = (b2 & 1) * 64;                  // k
        c0 = (b2 >> 1) * 64;                 // n
        src = qkv; dst = qT; sc = QKVN; sr = HDIM;
    } else {
        int b3 = bid - 1120;                 // 32 blocks: 16 r-tiles x 2 h-tiles
        r0 = (b3 >> 1) * 64;                 // r
        c0 = (b3 & 1) * 64;                  // h
        src = proj; dst = pT; sc = HDIM; sr = YN;
    }
    {   // load 64x64 f32 tile, convert, store to LDS (coalesced reads)
        int r = t >> 2, ch = (t & 3) * 16;
        const float* sp = src + (size_t)(r0 + r) * sc + c0 + ch;
        #pragma unroll
        for (int q = 0; q < 4; ++q) {
            float4 v = *(const float4*)(sp + q * 4);
            Ls[r][ch + q * 4 + 0] = f2bf(v.x);
            Ls[r][ch + q * 4 + 1] = f2bf(v.y);
            Ls[r][ch + q * 4 + 2] = f2bf(v.z);
            Ls[r][ch + q * 4 + 3] = f2bf(v.w);
        }
    }
    __syncthreads();
    {   // write transposed (coalesced writes)
        int dr = t >> 2, ch = (t & 3) * 16;
        short tmp[16];
        #pragma unroll
        for (int i = 0; i < 16; ++i) tmp[i] = Ls[ch + i][dr];
        short* dp = dst + (size_t)(c0 + dr) * sr + r0 + ch;
        *(int4*)dp       = *(int4*)&tmp[0];
        *(int4*)(dp + 8) = *(int4*)&tmp[8];
    }
}

// ---------------------------------------------------------------------------
// GEMM1 (r17 verbatim): XB(bf16) @ qkv -> per-head Qh/Kh/Vh, swapped-operand
// packed stores (16 x 8B cvt_pk stores/thread).
// ---------------------------------------------------------------------------
__global__ __launch_bounds__(256) void gemm_qkv(
    const short* __restrict__ XB, const short* __restrict__ qkvT,
    short* __restrict__ Qh, short* __restrict__ Kh, short* __restrict__ Vh)
{
    const int t = threadIdx.x, lane = t & 63, w = t >> 6;
    const int lr = lane & 15, lg = lane >> 4;
    const int m0 = blockIdx.x * 128 + (w >> 1) * 64;
    const int n0 = blockIdx.y * 128 + (w & 1) * 64;

    f32x4 acc[4][4];
    #pragma unroll
    for (int i = 0; i < 4; ++i)
        #pragma unroll
        for (int j = 0; j < 4; ++j) acc[i][j] = z4();

    #pragma unroll
    for (int c = 0; c < 4; ++c) {
        bfrag a[4], bb[4];
        #pragma unroll
        for (int rt = 0; rt < 4; ++rt)
            a[rt] = *(const bfrag*)(XB + (size_t)(m0 + rt * 16 + lr) * 128 + c * 32 + lg * 8);
        #pragma unroll
        for (int nt = 0; nt < 4; ++nt)
            bb[nt] = *(const bfrag*)(qkvT + (size_t)(n0 + nt * 16 + lr) * 128 + c * 32 + lg * 8);
        #pragma unroll
        for (int rt = 0; rt < 4; ++rt)
            #pragma unroll
            for (int nt = 0; nt < 4; ++nt)
                acc[rt][nt] = mfma16(bb[nt], a[rt], acc[rt][nt]);   // SWAPPED
    }

    const int part = blockIdx.y >> 3, c8 = blockIdx.y & 7;
    short* dst = (part == 0) ? Qh : ((part == 1) ? Kh : Vh);
    #pragma unroll
    for (int rt = 0; rt < 4; ++rt) {
        int m = m0 + rt * 16 + lr;
        int b = m >> 11, sl = m & 2047;
        int nh = sl >> 8, s2 = (sl & 255) * 8 + c8;
        size_t rowbase = ((size_t)((b * 8 + nh) * 2048 + s2)) * 128;
        #pragma unroll
        for (int nt = 0; nt < 4; ++nt) {
            int h0 = (w & 1) * 64 + nt * 16 + lg * 4;
            uint2 pk;
            pk.x = cvtpk(acc[rt][nt][0], acc[rt][nt][1]);
            pk.y = cvtpk(acc[rt][nt][2], acc[rt][nt][3]);
            *(uint2*)(dst + rowbase + h0) = pk;
        }
    }
}

// ---------------------------------------------------------------------------
// Transpose V per head: Vh[bn][s2][d] -> Vt[bn][d][s2]. (r13 verbatim)
// ---------------------------------------------------------------------------
__global__ __launch_bounds__(256) void transp_v(
    const short* __restrict__ Vh, short* __restrict__ Vt)
{
    __shared__ short Ls[64][72];
    const int bn = blockIdx.z, s20 = blockIdx.x * 64, d0 = blockIdx.y * 64;
    const int t = threadIdx.x;
    const short* src = Vh + ((size_t)bn * SEQ + s20) * 128 + d0;
    {
        int r = t >> 2, ch = (t & 3) * 16;
        *(int4*)&Ls[r][ch]     = *(const int4*)(src + (size_t)r * 128 + ch);
        *(int4*)&Ls[r][ch + 8] = *(const int4*)(src + (size_t)r * 128 + ch + 8);
    }
    __syncthreads();
    {
        int dr = t >> 2, ch = (t & 3) * 16;
        short tmp[16];
        #pragma unroll
        for (int i = 0; i < 16; ++i) tmp[i] = Ls[ch + i][dr];
        short* dp = Vt + ((size_t)bn * HDIM + d0 + dr) * SEQ + s20 + ch;
        *(int4*)dp       = *(int4*)&tmp[0];
        *(int4*)(dp + 8) = *(int4*)&tmp[8];
    }
}

// ---------------------------------------------------------------------------
// attn12 (r17/r19 verbatim — 81.4 us proven): 16 q-rows/wave, QBLK=64,
// tile-pairing (pp, 31-pp) -> 33 uniform steps, XCD affinity, K+V dbuf
// global_load_lds staging, one barrier/step, static kt + wave-uniform
// predicate, swapped QK^T in-register softmax, in-reg P redistribution,
// l via P*ones MFMA (C-layout), max3-shaped row-max, T13 defer-rescale.
// ---------------------------------------------------------------------------
__global__ __launch_bounds__(256) void attn12(
    const short* __restrict__ Qh, const short* __restrict__ Kh,
    const short* __restrict__ Vt, short* __restrict__ Y)
{
    __shared__ __align__(16) short Kls[2][64 * 128];   // 32 KB
    __shared__ __align__(16) short Vls[2][128 * 64];   // 32 KB

    const int t = threadIdx.x, lane = t & 63, w = t >> 6;
    const int lr = lane & 15, lg = lane >> 4;

    const int g  = blockIdx.x;        // 0..511
    const int bn = g & 31;            // head id; bn%8 == g%8 (XCD affinity)
    const int pp = g >> 5;            // pair id 0..15 -> tiles (pp, 31-pp)
    const int b  = bn >> 3, n = bn & 7;

    const short* Qb = Qh + (size_t)bn * SEQ * HDIM;
    const short* Kb = Kh + (size_t)bn * SEQ * HDIM;
    const short* Vb = Vt + (size_t)bn * HDIM * SEQ;

    auto stageK = [&](int buf, int k0) {
        #pragma unroll
        for (int i = 0; i < 4; ++i) {
            const int q = w * 4 + i;
            const int rowK = q * 4 + (lane >> 4);
            const short* src = Kb + (size_t)(k0 + rowK) * 128 + (((lane & 15) ^ (rowK & 7)) * 8);
            __builtin_amdgcn_global_load_lds(
                (const __attribute__((address_space(1))) unsigned int*)src,
                (__attribute__((address_space(3))) unsigned int*)&Kls[buf][q * 512 + lane * 8],
                16, 0, 0);
        }
    };
    auto stageV = [&](int buf, int k0) {
        #pragma unroll
        for (int i = 0; i < 4; ++i) {
            const int q = w * 4 + i;
            const int d = q * 8 + (lane >> 3);
            const short* src = Vb + (size_t)d * SEQ + k0 + (((lane & 7) ^ (d & 7)) * 8);
            __builtin_amdgcn_global_load_lds(
                (const __attribute__((address_space(1))) unsigned int*)src,
                (__attribute__((address_space(3))) unsigned int*)&Vls[buf][q * 512 + lane * 8],
                16, 0, 0);
        }
    };

    const int sw = lr & 7;
    const bool hi16 = (lg & 1);

    bfrag ones;
    #pragma unroll
    for (int k = 0; k < 8; ++k) ones[k] = (short)0x3F80;   // bf16 1.0

    #pragma unroll 1
    for (int phase = 0; phase < 2; ++phase) {
        const int tile = phase ? pp : (31 - pp);    // long tile first
        const int q0 = tile * 64 + w * 16;

        bfrag qf[4];
        #pragma unroll
        for (int c = 0; c < 4; ++c)
            qf[c] = *(const bfrag*)(Qb + (size_t)(q0 + lr) * 128 + c * 32 + lg * 8);

        float mcs = -1.0e30f;         // per-lane: q = q0 + lr
        f32x4 l4 = z4();              // C-layout row-sums
        f32x4 o[8];
        #pragma unroll
        for (int dt = 0; dt < 8; ++dt) o[dt] = z4();

        stageV(0, 0);
        stageK(0, 0);
        __syncthreads();   // buffer 0 staged

        for (int s = 0; s <= tile; ++s) {
            const int cur = s & 1;
            const int k0 = s * 64;
            if (s < tile) { stageV(cur ^ 1, k0 + 64); stageK(cur ^ 1, k0 + 64); }

            f32x4 sA[4];
            #pragma unroll
            for (int kt = 0; kt < 4; ++kt) sA[kt] = z4();
            const int ktend = (s == tile) ? (w + 1) : 4;
            __builtin_amdgcn_s_setprio(1);
            #pragma unroll
            for (int kt = 0; kt < 4; ++kt) {
                if (kt < ktend) {   // wave-uniform
                    const char* kbase = (const char*)&Kls[cur][0] + (kt * 16 + lr) * 256;
                    #pragma unroll
                    for (int c = 0; c < 4; ++c) {
                        bfrag kb = *(const bfrag*)(kbase + (((c * 4 + lg) ^ sw) * 16));
                        sA[kt] = mfma16(kb, qf[c], sA[kt]);   // swapped operands
                    }
                }
            }
            __builtin_amdgcn_s_setprio(0);

            if (s == tile) {
                #pragma unroll
                for (int kt = 0; kt < 4; ++kt)
                    #pragma unroll
                    for (int j = 0; j < 4; ++j)
                        if (kt * 16 + lg * 4 + j > w * 16 + lr)
                            sA[kt][j] = -3.0e38f;
            }

            // ---- row max: max3-shaped tree + 2 cross-lg shuffles
            float mx = fmaxf(fmaxf(sA[0][0], sA[0][1]), sA[0][2]);
            mx = fmaxf(fmaxf(mx, sA[0][3]), sA[1][0]);
            mx = fmaxf(fmaxf(mx, sA[1][1]), sA[1][2]);
            mx = fmaxf(fmaxf(mx, sA[1][3]), sA[2][0]);
            mx = fmaxf(fmaxf(mx, sA[2][1]), sA[2][2]);
            mx = fmaxf(fmaxf(mx, sA[2][3]), sA[3][0]);
            mx = fmaxf(fmaxf(mx, sA[3][1]), sA[3][2]);
            mx = fmaxf(mx, sA[3][3]);
            mx = fmaxf(mx, __shfl_xor(mx, 16));
            mx = fmaxf(mx, __shfl_xor(mx, 32));
            const float pmx = mx * CS;

            // ---- T13 defer-rescale (rare)
            if (__any((pmx > mcs + 8.0f) ? 1 : 0)) {
                float nm = fmaxf(mcs, pmx);
                float al = exp2f(mcs - nm);
                mcs = nm;
                float alj[4];
                #pragma unroll
                for (int j = 0; j < 4; ++j) alj[j] = __shfl(al, lg * 4 + j);
                #pragma unroll
                for (int j = 0; j < 4; ++j) l4[j] *= alj[j];
                #pragma unroll
                for (int dt = 0; dt < 8; ++dt)
                    #pragma unroll
                    for (int j = 0; j < 4; ++j) o[dt][j] *= alj[j];
            }

            // ---- P = exp2(S*CS - mcs) (lane-local row)
            float p[4][4];
            #pragma unroll
            for (int kt = 0; kt < 4; ++kt)
                #pragma unroll
                for (int j = 0; j < 4; ++j)
                    p[kt][j] = exp2f(sA[kt][j] * CS - mcs);

            bfrag pa0, pa1;
            redist(p, hi16, pa0, pa1);

            // ---- l via P*ones MFMA (C-layout, matrix pipe)
            l4 = mfma16(pa0, ones, mfma16(pa1, ones, l4));

            __builtin_amdgcn_s_setprio(1);
            #pragma unroll
            for (int dt = 0; dt < 8; ++dt) {
                const char* vbase = (const char*)&Vls[cur][0] + (dt * 16 + lr) * 128;
                bfrag vb0 = *(const bfrag*)(vbase + ((lg ^ sw) * 16));
                bfrag vb1 = *(const bfrag*)(vbase + (((4 + lg) ^ sw) * 16));
                o[dt] = mfma16(pa0, vb0, o[dt]);
                o[dt] = mfma16(pa1, vb1, o[dt]);
            }
            __builtin_amdgcn_s_setprio(0);

            __syncthreads();
        }

        // ---- epilogue: inv directly from C-layout l4 (no shuffles)
        float inv[4];
        #pragma unroll
        for (int j = 0; j < 4; ++j) inv[j] = 1.0f / l4[j];
        #pragma unroll
        for (int j = 0; j < 4; ++j) {
            int s2 = q0 + lg * 4 + j;
            size_t yrow = (size_t)b * SEQ + n * 256 + (s2 >> 3);
            short* yp = Y + yrow * YN + (s2 & 7) * 128 + lr;
            #pragma unroll
            for (int dt = 0; dt < 8; ++dt)
                yp[dt * 16] = f2bf(o[dt][j] * inv[j]);
        }
    }
}

// ---------------------------------------------------------------------------
// GEMM2 (r17 verbatim, swapped-operand float4 stores)
// ---------------------------------------------------------------------------
__global__ __launch_bounds__(128) void gemm_out(
    const short* __restrict__ Yb, const short* __restrict__ projT, float* __restrict__ out)
{
    const int t = threadIdx.x, lane = t & 63, w = t >> 6;   // w in 0..1
    const int lr = lane & 15, lg = lane >> 4;
    const int m0 = blockIdx.x * 16;
    const int n0 = w * 64;

    f32x4 acc[4];
    #pragma unroll
    for (int j = 0; j < 4; ++j) acc[j] = z4();

    for (int c = 0; c < 32; ++c) {
        bfrag a = *(const bfrag*)(Yb + (size_t)(m0 + lr) * YN + c * 32 + lg * 8);
        #pragma unroll
        for (int nt = 0; nt < 4; ++nt) {
            bfrag bb = *(const bfrag*)(projT + (size_t)(n0 + nt * 16 + lr) * YN + c * 32 + lg * 8);
            acc[nt] = mfma16(bb, a, acc[nt]);   // SWAPPED
        }
    }
    #pragma unroll
    for (int nt = 0; nt < 4; ++nt)
        *(f32x4*)(out + (size_t)(m0 + lr) * HDIM + n0 + nt * 16 + lg * 4) = acc[nt];
}

// ---------------------------------------------------------------------------
extern "C" void kernel_launch(void* const* d_in, const int* in_sizes, int n_in,
                              void* d_out, int out_size, void* d_ws, size_t ws_size,
                              hipStream_t stream)
{
    const float* x    = (const float*)d_in[0];  // [4,2048,128]
    const float* qkv  = (const float*)d_in[1];  // [128,3072]
    const float* proj = (const float*)d_in[2];  // [1024,128]
    float* out = (float*)d_out;                 // [8192,128]

    const size_t HEADSZ = (size_t)32 * SEQ * HDIM;        // 8,388,608 elements

    short* XB    = (short*)d_ws;                          // 2 MB
    short* qkvT  = XB    + (size_t)MROWS * HDIM;          // 0.75 MB
    short* projT = qkvT  + (size_t)QKVN * HDIM;           // 0.25 MB
    short* Qh    = projT + (size_t)HDIM * YN;             // 16 MB
    short* Kh    = Qh    + HEADSZ;                        // 16 MB
    short* Vh    = Kh    + HEADSZ;                        // 16 MB (row-major)
    short* Vtb   = Vh    + HEADSZ;                        // 16 MB (transposed)
    short* Yb    = Vtb   + HEADSZ;                        // 16 MB  (~83 MB total)

    conv_all<<<1152, 256, 0, stream>>>(x, qkv, proj, XB, qkvT, projT);
    gemm_qkv<<<dim3(MROWS / 128, QKVN / 128), 256, 0, stream>>>(XB, qkvT, Qh, Kh, Vh);
    transp_v<<<dim3(SEQ / 64, HDIM / 64, 32), 256, 0, stream>>>(Vh, Vtb);
    attn12  <<<512, 256, 0, stream>>>(Qh, Kh, Vtb, Yb);
    gemm_out<<<MROWS / 16, 128, 0, stream>>>(Yb, projT, out);
}

// Round 21
// 139.684 us; speedup vs baseline: 1.3507x; 1.0182x over previous
//
#include <hip/hip_runtime.h>
#include <math.h>

// Problem constants
#define BATCH 4
#define SEQ   2048
#define HDIM  128
#define NHEAD 8
#define MROWS (BATCH*SEQ)    // 8192
#define QKVN  (3*NHEAD*HDIM) // 3072
#define YN    (NHEAD*HDIM)   // 1024

#define CS 0.12751744f   // (1/sqrt(128)) * log2(e)

using bfrag = __attribute__((ext_vector_type(8))) short;  // 8 bf16 (4 VGPRs)
using f32x4 = __attribute__((ext_vector_type(4))) float;
using s16x4 = __attribute__((ext_vector_type(4))) short;

__device__ __forceinline__ f32x4 mfma16(bfrag a, bfrag b, f32x4 c) {
    return __builtin_amdgcn_mfma_f32_16x16x32_bf16(a, b, c, 0, 0, 0);
}
__device__ __forceinline__ short f2bf(float f) {
    union { float f; unsigned u; } v; v.f = f;
    unsigned r = v.u + 0x7FFFu + ((v.u >> 16) & 1u);  // RNE
    return (short)(r >> 16);
}
__device__ __forceinline__ unsigned cvtpk(float lo, float hi) {
    unsigned r;
    asm("v_cvt_pk_bf16_f32 %0, %1, %2" : "=v"(r) : "v"(lo), "v"(hi));
    return r;   // bits[15:0]=bf16(lo), bits[31:16]=bf16(hi)
}
__device__ __forceinline__ void perm32swap(unsigned &x, unsigned &y) {
    asm volatile("v_permlane32_swap_b32 %0, %1" : "+v"(x), "+v"(y));
}
__device__ __forceinline__ f32x4 z4() { f32x4 z; z[0]=0.f; z[1]=0.f; z[2]=0.f; z[3]=0.f; return z; }

// In-register P redistribution (C-layout -> A-frag layout), validated attn8/10/12.
__device__ __forceinline__ void redist(const float p[4][4], bool hi16,
                                       bfrag &pa0o, bfrag &pa1o) {
    unsigned pk0[2], pk1[2], pk2[2], pk3[2];
    pk0[0] = cvtpk(p[0][0], p[0][1]); pk0[1] = cvtpk(p[0][2], p[0][3]);
    pk1[0] = cvtpk(p[1][0], p[1][1]); pk1[1] = cvtpk(p[1][2], p[1][3]);
    pk2[0] = cvtpk(p[2][0], p[2][1]); pk2[1] = cvtpk(p[2][2], p[2][3]);
    pk3[0] = cvtpk(p[3][0], p[3][1]); pk3[1] = cvtpk(p[3][2], p[3][3]);
    uint4 w0, w1;
    {
        unsigned A = pk0[0], C = pk1[0];
        perm32swap(A, C);
        unsigned A16 = __shfl_xor((int)A, 16), C16 = __shfl_xor((int)C, 16);
        w0.x = hi16 ? C16 : A;
        w0.z = hi16 ? C   : A16;
        unsigned B = pk0[1], D = pk1[1];
        perm32swap(B, D);
        unsigned B16 = __shfl_xor((int)B, 16), D16 = __shfl_xor((int)D, 16);
        w0.y = hi16 ? D16 : B;
        w0.w = hi16 ? D   : B16;
    }
    {
        unsigned E = pk2[0], G = pk3[0];
        perm32swap(E, G);
        unsigned E16 = __shfl_xor((int)E, 16), G16 = __shfl_xor((int)G, 16);
        w1.x = hi16 ? G16 : E;
        w1.z = hi16 ? G   : E16;
        unsigned F = pk2[1], H = pk3[1];
        perm32swap(F, H);
        unsigned F16 = __shfl_xor((int)F, 16), H16 = __shfl_xor((int)H, 16);
        w1.y = hi16 ? H16 : F;
        w1.w = hi16 ? H   : F16;
    }
    union { uint4 u; bfrag f; } cv0, cv1;
    cv0.u = w0; cv1.u = w1;
    pa0o = cv0.f; pa1o = cv1.f;
}

// ---------------------------------------------------------------------------
// Merged converters, all COALESCED (r20 verbatim).
// ---------------------------------------------------------------------------
__global__ __launch_bounds__(256) void conv_all(
    const float* __restrict__ x, const float* __restrict__ qkv,
    const float* __restrict__ proj, short* __restrict__ XB,
    short* __restrict__ qT, short* __restrict__ pT)
{
    __shared__ short Ls[64][72];
    const int bid = blockIdx.x, t = threadIdx.x;
    if (bid < 1024) {
        int i = (bid * 256 + t) * 4;
        float4 v = *(const float4*)(x + i);
        s16x4 o; o[0] = f2bf(v.x); o[1] = f2bf(v.y); o[2] = f2bf(v.z); o[3] = f2bf(v.w);
        *(s16x4*)(XB + i) = o;
        return;
    }
    const float* src;
    short* dst;
    int r0, c0, sc, sr;
    if (bid < 1120) {
        int b2 = bid - 1024;
        r0 = (b2 & 1) * 64;
        c0 = (b2 >> 1) * 64;
        src = qkv; dst = qT; sc = QKVN; sr = HDIM;
    } else {
        int b3 = bid - 1120;
        r0 = (b3 >> 1) * 64;
        c0 = (b3 & 1) * 64;
        src = proj; dst = pT; sc = HDIM; sr = YN;
    }
    {
        int r = t >> 2, ch = (t & 3) * 16;
        const float* sp = src + (size_t)(r0 + r) * sc + c0 + ch;
        #pragma unroll
        for (int q = 0; q < 4; ++q) {
            float4 v = *(const float4*)(sp + q * 4);
            Ls[r][ch + q * 4 + 0] = f2bf(v.x);
            Ls[r][ch + q * 4 + 1] = f2bf(v.y);
            Ls[r][ch + q * 4 + 2] = f2bf(v.z);
            Ls[r][ch + q * 4 + 3] = f2bf(v.w);
        }
    }
    __syncthreads();
    {
        int dr = t >> 2, ch = (t & 3) * 16;
        short tmp[16];
        #pragma unroll
        for (int i = 0; i < 16; ++i) tmp[i] = Ls[ch + i][dr];
        short* dp = dst + (size_t)(c0 + dr) * sr + r0 + ch;
        *(int4*)dp       = *(int4*)&tmp[0];
        *(int4*)(dp + 8) = *(int4*)&tmp[8];
    }
}

// ---------------------------------------------------------------------------
// GEMM1 (r17 verbatim): XB(bf16) @ qkv -> per-head Qh/Kh/Vh, swapped-operand
// packed stores.
// ---------------------------------------------------------------------------
__global__ __launch_bounds__(256) void gemm_qkv(
    const short* __restrict__ XB, const short* __restrict__ qkvT,
    short* __restrict__ Qh, short* __restrict__ Kh, short* __restrict__ Vh)
{
    const int t = threadIdx.x, lane = t & 63, w = t >> 6;
    const int lr = lane & 15, lg = lane >> 4;
    const int m0 = blockIdx.x * 128 + (w >> 1) * 64;
    const int n0 = blockIdx.y * 128 + (w & 1) * 64;

    f32x4 acc[4][4];
    #pragma unroll
    for (int i = 0; i < 4; ++i)
        #pragma unroll
        for (int j = 0; j < 4; ++j) acc[i][j] = z4();

    #pragma unroll
    for (int c = 0; c < 4; ++c) {
        bfrag a[4], bb[4];
        #pragma unroll
        for (int rt = 0; rt < 4; ++rt)
            a[rt] = *(const bfrag*)(XB + (size_t)(m0 + rt * 16 + lr) * 128 + c * 32 + lg * 8);
        #pragma unroll
        for (int nt = 0; nt < 4; ++nt)
            bb[nt] = *(const bfrag*)(qkvT + (size_t)(n0 + nt * 16 + lr) * 128 + c * 32 + lg * 8);
        #pragma unroll
        for (int rt = 0; rt < 4; ++rt)
            #pragma unroll
            for (int nt = 0; nt < 4; ++nt)
                acc[rt][nt] = mfma16(bb[nt], a[rt], acc[rt][nt]);   // SWAPPED
    }

    const int part = blockIdx.y >> 3, c8 = blockIdx.y & 7;
    short* dst = (part == 0) ? Qh : ((part == 1) ? Kh : Vh);
    #pragma unroll
    for (int rt = 0; rt < 4; ++rt) {
        int m = m0 + rt * 16 + lr;
        int b = m >> 11, sl = m & 2047;
        int nh = sl >> 8, s2 = (sl & 255) * 8 + c8;
        size_t rowbase = ((size_t)((b * 8 + nh) * 2048 + s2)) * 128;
        #pragma unroll
        for (int nt = 0; nt < 4; ++nt) {
            int h0 = (w & 1) * 64 + nt * 16 + lg * 4;
            uint2 pk;
            pk.x = cvtpk(acc[rt][nt][0], acc[rt][nt][1]);
            pk.y = cvtpk(acc[rt][nt][2], acc[rt][nt][3]);
            *(uint2*)(dst + rowbase + h0) = pk;
        }
    }
}

// ---------------------------------------------------------------------------
// Transpose V per head: Vh[bn][s2][d] -> Vt[bn][d][s2]. (r13 verbatim)
// ---------------------------------------------------------------------------
__global__ __launch_bounds__(256) void transp_v(
    const short* __restrict__ Vh, short* __restrict__ Vt)
{
    __shared__ short Ls[64][72];
    const int bn = blockIdx.z, s20 = blockIdx.x * 64, d0 = blockIdx.y * 64;
    const int t = threadIdx.x;
    const short* src = Vh + ((size_t)bn * SEQ + s20) * 128 + d0;
    {
        int r = t >> 2, ch = (t & 3) * 16;
        *(int4*)&Ls[r][ch]     = *(const int4*)(src + (size_t)r * 128 + ch);
        *(int4*)&Ls[r][ch + 8] = *(const int4*)(src + (size_t)r * 128 + ch + 8);
    }
    __syncthreads();
    {
        int dr = t >> 2, ch = (t & 3) * 16;
        short tmp[16];
        #pragma unroll
        for (int i = 0; i < 16; ++i) tmp[i] = Ls[ch + i][dr];
        short* dp = Vt + ((size_t)bn * HDIM + d0 + dr) * SEQ + s20 + ch;
        *(int4*)dp       = *(int4*)&tmp[0];
        *(int4*)(dp + 8) = *(int4*)&tmp[8];
    }
}

// ---------------------------------------------------------------------------
// attn15 = attn12 compute body with RACE-FREE single-buffered V + 3 blocks/CU:
//  - Vls single buffer (16 KB) + Kls dbuf (32 KB) = 48 KB -> 3 blocks/CU.
//  - 1024 single-tile blocks (no pairing), work-descending (tile = 31-(g>>5)),
//    XCD-affine (bn%8 == g%8) -> the extra residency is actually usable.
//  - 2 barriers/step: B2 between softmax and PV (each wave's own vmcnt(0)
//    drain at the barrier => ALL waves' stageV(s) writes visible before any
//    PV(s) read); B1 after PV (all V reads done => Vls free for stageV(s+1)).
//    Every cross-wave visibility edge crosses a barrier — unlike attn8/14.
//  - K(s+1) prefetch spans QK^T+softmax; V(s+1) loads span B1->B2 of s+1.
// ---------------------------------------------------------------------------
__global__ __launch_bounds__(256) void attn15(
    const short* __restrict__ Qh, const short* __restrict__ Kh,
    const short* __restrict__ Vt, short* __restrict__ Y)
{
    __shared__ __align__(16) short Kls[2][64 * 128];   // 32 KB (dbuf)
    __shared__ __align__(16) short Vls[128 * 64];      // 16 KB (single)

    const int t = threadIdx.x, lane = t & 63, w = t >> 6;
    const int lr = lane & 15, lg = lane >> 4;

    const int g  = blockIdx.x;        // 0..1023
    const int bn = g & 31;            // head id; bn%8 == g%8 (XCD affinity)
    const int tile = 31 - (g >> 5);   // 64-row q-tile, work-descending
    const int b  = bn >> 3, n = bn & 7;
    const int q0 = tile * 64 + w * 16;

    const short* Qb = Qh + (size_t)bn * SEQ * HDIM;
    const short* Kb = Kh + (size_t)bn * SEQ * HDIM;
    const short* Vb = Vt + (size_t)bn * HDIM * SEQ;

    auto stageK = [&](int buf, int k0) {
        #pragma unroll
        for (int i = 0; i < 4; ++i) {
            const int q = w * 4 + i;
            const int rowK = q * 4 + (lane >> 4);
            const short* src = Kb + (size_t)(k0 + rowK) * 128 + (((lane & 15) ^ (rowK & 7)) * 8);
            __builtin_amdgcn_global_load_lds(
                (const __attribute__((address_space(1))) unsigned int*)src,
                (__attribute__((address_space(3))) unsigned int*)&Kls[buf][q * 512 + lane * 8],
                16, 0, 0);
        }
    };
    auto stageV = [&](int k0) {
        #pragma unroll
        for (int i = 0; i < 4; ++i) {
            const int q = w * 4 + i;
            const int d = q * 8 + (lane >> 3);
            const short* src = Vb + (size_t)d * SEQ + k0 + (((lane & 7) ^ (d & 7)) * 8);
            __builtin_amdgcn_global_load_lds(
                (const __attribute__((address_space(1))) unsigned int*)src,
                (__attribute__((address_space(3))) unsigned int*)&Vls[q * 512 + lane * 8],
                16, 0, 0);
        }
    };

    const int sw = lr & 7;
    const bool hi16 = (lg & 1);

    bfrag ones;
    #pragma unroll
    for (int k = 0; k < 8; ++k) ones[k] = (short)0x3F80;   // bf16 1.0

    bfrag qf[4];
    #pragma unroll
    for (int c = 0; c < 4; ++c)
        qf[c] = *(const bfrag*)(Qb + (size_t)(q0 + lr) * 128 + c * 32 + lg * 8);

    float mcs = -1.0e30f;         // per-lane: q = q0 + lr
    f32x4 l4 = z4();              // C-layout row-sums
    f32x4 o[8];
    #pragma unroll
    for (int dt = 0; dt < 8; ++dt) o[dt] = z4();

    stageV(0);
    stageK(0, 0);
    __syncthreads();   // prologue: step-0 K and V staged (own vmcnt drained)

    for (int s = 0; s <= tile; ++s) {
        const int cur = s & 1;
        const int k0 = s * 64;
        if (s < tile) stageK(cur ^ 1, k0 + 64);   // K prefetch, spans this step

        f32x4 sA[4];
        #pragma unroll
        for (int kt = 0; kt < 4; ++kt) sA[kt] = z4();
        const int ktend = (s == tile) ? (w + 1) : 4;
        __builtin_amdgcn_s_setprio(1);
        #pragma unroll
        for (int kt = 0; kt < 4; ++kt) {
            if (kt < ktend) {   // wave-uniform
                const char* kbase = (const char*)&Kls[cur][0] + (kt * 16 + lr) * 256;
                #pragma unroll
                for (int c = 0; c < 4; ++c) {
                    bfrag kb = *(const bfrag*)(kbase + (((c * 4 + lg) ^ sw) * 16));
                    sA[kt] = mfma16(kb, qf[c], sA[kt]);   // swapped operands
                }
            }
        }
        __builtin_amdgcn_s_setprio(0);

        if (s == tile) {
            #pragma unroll
            for (int kt = 0; kt < 4; ++kt)
                #pragma unroll
                for (int j = 0; j < 4; ++j)
                    if (kt * 16 + lg * 4 + j > w * 16 + lr)
                        sA[kt][j] = -3.0e38f;
        }

        // ---- row max: max3-shaped tree + 2 cross-lg shuffles
        float mx = fmaxf(fmaxf(sA[0][0], sA[0][1]), sA[0][2]);
        mx = fmaxf(fmaxf(mx, sA[0][3]), sA[1][0]);
        mx = fmaxf(fmaxf(mx, sA[1][1]), sA[1][2]);
        mx = fmaxf(fmaxf(mx, sA[1][3]), sA[2][0]);
        mx = fmaxf(fmaxf(mx, sA[2][1]), sA[2][2]);
        mx = fmaxf(fmaxf(mx, sA[2][3]), sA[3][0]);
        mx = fmaxf(fmaxf(mx, sA[3][1]), sA[3][2]);
        mx = fmaxf(mx, sA[3][3]);
        mx = fmaxf(mx, __shfl_xor(mx, 16));
        mx = fmaxf(mx, __shfl_xor(mx, 32));
        const float pmx = mx * CS;

        // ---- T13 defer-rescale (rare)
        if (__any((pmx > mcs + 8.0f) ? 1 : 0)) {
            float nm = fmaxf(mcs, pmx);
            float al = exp2f(mcs - nm);
            mcs = nm;
            float alj[4];
            #pragma unroll
            for (int j = 0; j < 4; ++j) alj[j] = __shfl(al, lg * 4 + j);
            #pragma unroll
            for (int j = 0; j < 4; ++j) l4[j] *= alj[j];
            #pragma unroll
            for (int dt = 0; dt < 8; ++dt)
                #pragma unroll
                for (int j = 0; j < 4; ++j) o[dt][j] *= alj[j];
        }

        // ---- P = exp2(S*CS - mcs) (lane-local row)
        float p[4][4];
        #pragma unroll
        for (int kt = 0; kt < 4; ++kt)
            #pragma unroll
            for (int j = 0; j < 4; ++j)
                p[kt][j] = exp2f(sA[kt][j] * CS - mcs);

        bfrag pa0, pa1;
        redist(p, hi16, pa0, pa1);

        // ---- l via P*ones MFMA (C-layout, matrix pipe)
        l4 = mfma16(pa0, ones, mfma16(pa1, ones, l4));

        __syncthreads();   // B2: own vmcnt(0) drain per wave -> ALL stageV(s)
                           // writes visible to every wave before PV reads

        // ---- PV from single Vls
        __builtin_amdgcn_s_setprio(1);
        #pragma unroll
        for (int dt = 0; dt < 8; ++dt) {
            const char* vbase = (const char*)&Vls[0] + (dt * 16 + lr) * 128;
            bfrag vb0 = *(const bfrag*)(vbase + ((lg ^ sw) * 16));
            bfrag vb1 = *(const bfrag*)(vbase + (((4 + lg) ^ sw) * 16));
            o[dt] = mfma16(pa0, vb0, o[dt]);
            o[dt] = mfma16(pa1, vb1, o[dt]);
        }
        __builtin_amdgcn_s_setprio(0);

        __syncthreads();   // B1: all PV reads done -> Vls free
        if (s < tile) stageV(k0 + 64);   // V(s+1); drains at B2 of step s+1
    }

    // ---- epilogue: inv directly from C-layout l4 (no shuffles)
    float inv[4];
    #pragma unroll
    for (int j = 0; j < 4; ++j) inv[j] = 1.0f / l4[j];
    #pragma unroll
    for (int j = 0; j < 4; ++j) {
        int s2 = q0 + lg * 4 + j;
        size_t yrow = (size_t)b * SEQ + n * 256 + (s2 >> 3);
        short* yp = Y + yrow * YN + (s2 & 7) * 128 + lr;
        #pragma unroll
        for (int dt = 0; dt < 8; ++dt)
            yp[dt * 16] = f2bf(o[dt][j] * inv[j]);
    }
}

// ---------------------------------------------------------------------------
// GEMM2 (r17 verbatim, swapped-operand float4 stores)
// ---------------------------------------------------------------------------
__global__ __launch_bounds__(128) void gemm_out(
    const short* __restrict__ Yb, const short* __restrict__ projT, float* __restrict__ out)
{
    const int t = threadIdx.x, lane = t & 63, w = t >> 6;   // w in 0..1
    const int lr = lane & 15, lg = lane >> 4;
    const int m0 = blockIdx.x * 16;
    const int n0 = w * 64;

    f32x4 acc[4];
    #pragma unroll
    for (int j = 0; j < 4; ++j) acc[j] = z4();

    for (int c = 0; c < 32; ++c) {
        bfrag a = *(const bfrag*)(Yb + (size_t)(m0 + lr) * YN + c * 32 + lg * 8);
        #pragma unroll
        for (int nt = 0; nt < 4; ++nt) {
            bfrag bb = *(const bfrag*)(projT + (size_t)(n0 + nt * 16 + lr) * YN + c * 32 + lg * 8);
            acc[nt] = mfma16(bb, a, acc[nt]);   // SWAPPED
        }
    }
    #pragma unroll
    for (int nt = 0; nt < 4; ++nt)
        *(f32x4*)(out + (size_t)(m0 + lr) * HDIM + n0 + nt * 16 + lg * 4) = acc[nt];
}

// ---------------------------------------------------------------------------
extern "C" void kernel_launch(void* const* d_in, const int* in_sizes, int n_in,
                              void* d_out, int out_size, void* d_ws, size_t ws_size,
                              hipStream_t stream)
{
    const float* x    = (const float*)d_in[0];  // [4,2048,128]
    const float* qkv  = (const float*)d_in[1];  // [128,3072]
    const float* proj = (const float*)d_in[2];  // [1024,128]
    float* out = (float*)d_out;                 // [8192,128]

    const size_t HEADSZ = (size_t)32 * SEQ * HDIM;        // 8,388,608 elements

    short* XB    = (short*)d_ws;                          // 2 MB
    short* qkvT  = XB    + (size_t)MROWS * HDIM;          // 0.75 MB
    short* projT = qkvT  + (size_t)QKVN * HDIM;           // 0.25 MB
    short* Qh    = projT + (size_t)HDIM * YN;             // 16 MB
    short* Kh    = Qh    + HEADSZ;                        // 16 MB
    short* Vh    = Kh    + HEADSZ;                        // 16 MB (row-major)
    short* Vtb   = Vh    + HEADSZ;                        // 16 MB (transposed)
    short* Yb    = Vtb   + HEADSZ;                        // 16 MB  (~83 MB total)

    conv_all<<<1152, 256, 0, stream>>>(x, qkv, proj, XB, qkvT, projT);
    gemm_qkv<<<dim3(MROWS / 128, QKVN / 128), 256, 0, stream>>>(XB, qkvT, Qh, Kh, Vh);
    transp_v<<<dim3(SEQ / 64, HDIM / 64, 32), 256, 0, stream>>>(Vh, Vtb);
    attn15  <<<1024, 256, 0, stream>>>(Qh, Kh, Vtb, Yb);
    gemm_out<<<MROWS / 16, 128, 0, stream>>>(Yb, projT, out);
}